// Round 10
// baseline (1008.502 us; speedup 1.0000x reference)
//
#include <hip/hip_runtime.h>

// B=512, T-1=128, D=128, H=512. softmax(proj_x + shift[:,None]) == softmax(proj_x)
// => attention is timestep-invariant; only the LSTM recurrence is sequential.
//
// R10 = R3 (552us, proven: 8 groups x 32 slices, 64x16 block, LDS-staged h,
// MALL sc0 sc1 hand-off) with the sync convoy dismantled, nothing else:
//  (1) barriers 4 -> 2: (a) removed (ALL waves poll one group counter),
//      (d) removed (per-wave vmcnt(0) + lane0 atomicAdd arrival counter;
//      consumer target = 256*t = 32 blocks x 8 waves).
//  (2) wi-MFMAs hoisted ABOVE the poll (overlap producers' tails); WT
//      double-buffered by t-parity to make that safe.
//  (3) v_cvt_pk_bf16_f32 for bf16 packing.
// Geometry, fragments, staging, pointwise = R3 verbatim.

typedef __attribute__((ext_vector_type(8))) short short8;
typedef __attribute__((ext_vector_type(4))) float floatx4;
typedef __attribute__((ext_vector_type(4))) unsigned int uintx4;

#define NB 512
#define NT 128
#define ND 128
#define NH 512

// LDS layout (132096 B <= 160K; > 81920 => 1 block/CU)
#define HH_OFF 0          // h tile [64][512] bf16, swizzled (64 KB)
#define WT0_OFF 65536     // wi tile ping [64][128] bf16, swizzled (16 KB)
#define WT1_OFF 81920     // wi tile pong (16 KB)
#define GT_OFF 98304      // gates [2 kh][64][66] f32 (33792 B)
#define GT_KH  16896
#define LDS_BYTES 132096

static __device__ __forceinline__ unsigned short f2bf(float f) {
  unsigned int u = __float_as_uint(f);
  u += 0x7fffu + ((u >> 16) & 1u);   // RNE
  return (unsigned short)(u >> 16);
}
static __device__ __forceinline__ unsigned int cvtpk(float lo, float hi) {
  unsigned int r;
  asm("v_cvt_pk_bf16_f32 %0, %1, %2" : "=v"(r) : "v"(lo), "v"(hi));
  return r;
}
static __device__ __forceinline__ float sigf(float x) {
  return 1.f / (1.f + __expf(-x));
}
static __device__ __forceinline__ float tanh_fast(float x) {
  const float e = __expf(-2.f * fabsf(x));
  const float r = (1.f - e) / (1.f + e);
  return copysignf(r, x);
}

// ---------------------------------------------------------------------------
// Kernel A: attn[b,d] = softmax_d( sum_t in[b,t,d]*wx[t] ); out0 = attn*in
// ---------------------------------------------------------------------------
__global__ __launch_bounds__(128) void attn_kernel(
    const float* __restrict__ in, const float* __restrict__ attn_W,
    float* __restrict__ out0, float* __restrict__ attn_ws) {
  const int b = blockIdx.x;
  const int d = threadIdx.x;
  __shared__ float wx[NT];
  __shared__ float red[4];
  wx[d] = attn_W[2 * NH + d];
  __syncthreads();
  const float* ib = in + (size_t)b * (NT * ND);
  float p = 0.f;
#pragma unroll 8
  for (int t = 0; t < NT; ++t) p = fmaf(ib[t * ND + d], wx[t], p);
  float m = p;
#pragma unroll
  for (int off = 32; off >= 1; off >>= 1) m = fmaxf(m, __shfl_xor(m, off));
  const int wv = d >> 6;
  if ((d & 63) == 0) red[wv] = m;
  __syncthreads();
  const float M = fmaxf(red[0], red[1]);
  const float e = expf(p - M);
  float s = e;
#pragma unroll
  for (int off = 32; off >= 1; off >>= 1) s += __shfl_xor(s, off);
  if ((d & 63) == 0) red[2 + wv] = s;
  __syncthreads();
  const float a = e / (red[2] + red[3]);
  attn_ws[b * ND + d] = a;
#pragma unroll 4
  for (int t = 0; t < NT; ++t)
    out0[(size_t)b * (NT * ND) + t * ND + d] = a * ib[t * ND + d];
}

// ---------------------------------------------------------------------------
// Kernel C: persistent fused LSTM recurrence. 256 blocks x 512 thr, 1/CU.
// Block (gid=bid&7, sid=bid>>3): batch rows [gid*64,+64), h-cols [sid*16,+16).
// Wave wid: rw=wid&1 (row half), cg=(wid>>1)&1 (gate pair), kh=wid>>2 (K half).
// W fragments in registers (bh[8][2], bwi[2][2]); h + wi + gates in LDS.
// ---------------------------------------------------------------------------
__global__ __launch_bounds__(512, 2) void rec_kernel(
    const float* __restrict__ in, const float* __restrict__ W_ih,
    const float* __restrict__ W_hh, const float* __restrict__ b_ih,
    const float* __restrict__ b_hh, const float* __restrict__ attn_ws,
    unsigned short* __restrict__ hbuf, unsigned int* __restrict__ flags,
    float* __restrict__ out1) {
  __shared__ __align__(16) unsigned char LDS[LDS_BYTES];
  const int tid = threadIdx.x;
  const int bid = blockIdx.x;
  const int gid = bid & 7;
  const int sid = bid >> 3;
  const int bb0 = gid * 64;
  const int n0 = sid * 16;
  const int lane = tid & 63;
  const int wid = tid >> 6;
  const int rw = wid & 1;
  const int cg = (wid >> 1) & 1;
  const int kh = wid >> 2;
  const int colB = lane & 15;
  const int kg = lane >> 4;

  // --- W fragments -> registers (one-time), R3 verbatim ---
  short8 bh[8][2];
  short8 bwi[2][2];
#pragma unroll
  for (int j = 0; j < 2; ++j) {
    const int gate = cg * 2 + j;
    const float* wr_h = W_hh + (size_t)(gate * NH + n0 + colB) * NH;
    const float* wr_i = W_ih + (size_t)(gate * NH + n0 + colB) * ND;
#pragma unroll
    for (int ksl = 0; ksl < 8; ++ksl) {
      const int k0 = (kh * 8 + ksl) * 32 + kg * 8;
      floatx4 f0 = *(const floatx4*)(wr_h + k0);
      floatx4 f1 = *(const floatx4*)(wr_h + k0 + 4);
      short8 s;
#pragma unroll
      for (int i = 0; i < 4; ++i) {
        s[i] = (short)f2bf(f0[i]);
        s[4 + i] = (short)f2bf(f1[i]);
      }
      bh[ksl][j] = s;
    }
#pragma unroll
    for (int ksl = 0; ksl < 2; ++ksl) {
      const int k0 = (kh * 2 + ksl) * 32 + kg * 8;
      floatx4 f0 = *(const floatx4*)(wr_i + k0);
      floatx4 f1 = *(const floatx4*)(wr_i + k0 + 4);
      short8 s;
#pragma unroll
      for (int i = 0; i < 4; ++i) {
        s[i] = (short)f2bf(f0[i]);
        s[4 + i] = (short)f2bf(f1[i]);
      }
      bwi[ksl][j] = s;
    }
  }

  // --- attention weights (t-invariant) ---
  const int rA = tid >> 3;
  const int pA = tid & 7;
  float areg[16];
  {
    const float* ap = attn_ws + (bb0 + rA) * ND + pA * 16;
#pragma unroll
    for (int i = 0; i < 16; ++i) areg[i] = ap[i];
  }
  // --- biases ---
  const int colC = tid & 15;
  const int jC = n0 + colC;
  const float bi_i = b_ih[jC] + b_hh[jC];
  const float bi_f = b_ih[NH + jC] + b_hh[NH + jC];
  const float bi_g = b_ih[2 * NH + jC] + b_hh[2 * NH + jC];
  const float bi_o = b_ih[3 * NH + jC] + b_hh[3 * NH + jC];
  float creg0 = 0.f, creg1 = 0.f;

  const int rowa0 = rw * 32 + colB;
  const int rowa1 = rowa0 + 16;
  const int swa = (rowa0 & 7) << 4;
  const int prow = tid >> 4;
  unsigned int* cptr = flags + gid * 32;     // per-group arrival counter

  // --- prologue: WT0 <- wi_0; prefetch x_1 ---
  floatx4 xr4[4];
  {
    const float* xs = in + ((size_t)(bb0 + rA) * NT + 0) * ND + pA * 16;
#pragma unroll
    for (int i = 0; i < 4; ++i) xr4[i] = *(const floatx4*)(xs + 4 * i);
    unsigned int w[8];
#pragma unroll
    for (int i = 0; i < 8; ++i)
      w[i] = cvtpk(xr4[i >> 1][(i & 1) * 2 + 0] * areg[2 * i],
                   xr4[i >> 1][(i & 1) * 2 + 1] * areg[2 * i + 1]);
    const int base = WT0_OFF + rA * 256;
    const int swp = (rA & 7) << 4;
    uintx4 lo = {w[0], w[1], w[2], w[3]};
    uintx4 hi = {w[4], w[5], w[6], w[7]};
    *(uintx4*)&LDS[base + ((pA * 32) ^ swp)] = lo;
    *(uintx4*)&LDS[base + ((pA * 32 + 16) ^ swp)] = hi;
  }
  {
    const float* xs = in + ((size_t)(bb0 + rA) * NT + 1) * ND + pA * 16;
#pragma unroll
    for (int i = 0; i < 4; ++i) xr4[i] = *(const floatx4*)(xs + 4 * i);
  }
  __syncthreads();

  for (int t = 0; t < NT; ++t) {
    const int wtR = WT0_OFF + ((t & 1) ? (WT1_OFF - WT0_OFF) : 0);
    const int wtW = WT0_OFF + ((t & 1) ? 0 : (WT1_OFF - WT0_OFF));

    floatx4 acc00 = {0.f, 0.f, 0.f, 0.f};
    floatx4 acc01 = {0.f, 0.f, 0.f, 0.f};
    floatx4 acc10 = {0.f, 0.f, 0.f, 0.f};
    floatx4 acc11 = {0.f, 0.f, 0.f, 0.f};

    // ---- P1: wi MFMAs (pre-poll; WT[t&1] stable since B1 of t-1) ----
#pragma unroll
    for (int ksl = 0; ksl < 2; ++ksl) {
      const int k2 = (kh * 2 + ksl) * 64 + kg * 16;
      short8 a0 = *(const short8*)&LDS[wtR + rowa0 * 256 + (k2 ^ swa)];
      short8 a1 = *(const short8*)&LDS[wtR + rowa1 * 256 + (k2 ^ swa)];
      acc00 = __builtin_amdgcn_mfma_f32_16x16x32_bf16(a0, bwi[ksl][0], acc00, 0, 0, 0);
      acc01 = __builtin_amdgcn_mfma_f32_16x16x32_bf16(a0, bwi[ksl][1], acc01, 0, 0, 0);
      acc10 = __builtin_amdgcn_mfma_f32_16x16x32_bf16(a1, bwi[ksl][0], acc10, 0, 0, 0);
      acc11 = __builtin_amdgcn_mfma_f32_16x16x32_bf16(a1, bwi[ksl][1], acc11, 0, 0, 0);
    }
    // ---- pack wi_{t+1} (pre-poll VALU) ----
    unsigned int w[8];
#pragma unroll
    for (int i = 0; i < 8; ++i)
      w[i] = cvtpk(xr4[i >> 1][(i & 1) * 2 + 0] * areg[2 * i],
                   xr4[i >> 1][(i & 1) * 2 + 1] * areg[2 * i + 1]);

    if (t > 0) {
      // ---- P2: poll (ALL waves, one dword, MALL-coherent) ----
      const unsigned int target = (unsigned int)(t << 8);   // 256*t
      unsigned int v;
      do {
        asm volatile("global_load_dword %0, %1, off sc0 sc1\n\ts_waitcnt vmcnt(0)"
                     : "=v"(v) : "v"(cptr) : "memory");
      } while (v < target);
      __builtin_amdgcn_sched_barrier(0);
      // ---- P3: h gather (8 x 16B coalesced) ----
      const unsigned short* hsrc = hbuf + ((t & 1) ? (size_t)(NB * NH) : 0);
      uintx4 hq[8];
#pragma unroll
      for (int p = 0; p < 8; ++p) {
        const int idx = p * 512 + tid;
        const int r = idx >> 6, s = idx & 63;
        const unsigned short* src = hsrc + (size_t)(bb0 + r) * NH + s * 8;
        asm volatile("global_load_dwordx4 %0, %1, off sc0 sc1"
                     : "=v"(hq[p]) : "v"(src) : "memory");
      }
      asm volatile("s_waitcnt vmcnt(0)" ::: "memory");
      __builtin_amdgcn_sched_barrier(0);
      // ---- P4: HH stage ----
#pragma unroll
      for (int p = 0; p < 8; ++p) {
        const int idx = p * 512 + tid;
        const int r = idx >> 6, s = idx & 63;
        *(uintx4*)&LDS[HH_OFF + r * 1024 + ((s * 16) ^ ((r & 7) << 4))] = hq[p];
      }
    }
    // ---- P5: WT[(t+1)&1] <- wi_{t+1} ----
    {
      const int base = wtW + rA * 256;
      const int swp = (rA & 7) << 4;
      uintx4 lo = {w[0], w[1], w[2], w[3]};
      uintx4 hi = {w[4], w[5], w[6], w[7]};
      *(uintx4*)&LDS[base + ((pA * 32) ^ swp)] = lo;
      *(uintx4*)&LDS[base + ((pA * 32 + 16) ^ swp)] = hi;
    }
    __syncthreads();                                   // B1
    // ---- P6: h MFMAs ----
    if (t > 0) {
#pragma unroll
      for (int ksl = 0; ksl < 8; ++ksl) {
        const int k2 = (kh * 8 + ksl) * 64 + kg * 16;
        short8 a0 = *(const short8*)&LDS[HH_OFF + rowa0 * 1024 + (k2 ^ swa)];
        short8 a1 = *(const short8*)&LDS[HH_OFF + rowa1 * 1024 + (k2 ^ swa)];
        acc00 = __builtin_amdgcn_mfma_f32_16x16x32_bf16(a0, bh[ksl][0], acc00, 0, 0, 0);
        acc01 = __builtin_amdgcn_mfma_f32_16x16x32_bf16(a0, bh[ksl][1], acc01, 0, 0, 0);
        acc10 = __builtin_amdgcn_mfma_f32_16x16x32_bf16(a1, bh[ksl][0], acc10, 0, 0, 0);
        acc11 = __builtin_amdgcn_mfma_f32_16x16x32_bf16(a1, bh[ksl][1], acc11, 0, 0, 0);
      }
    }
    // ---- P7: gate partials -> GT[kh][64][66] ----
#pragma unroll
    for (int i = 0; i < 2; ++i)
#pragma unroll
      for (int r = 0; r < 4; ++r) {
        const int row = rw * 32 + i * 16 + kg * 4 + r;
        const int c0 = cg * 32 + colB;
        const floatx4& aL = i ? acc10 : acc00;
        const floatx4& aR = i ? acc11 : acc01;
        *(float*)&LDS[GT_OFF + kh * GT_KH + (row * 66 + c0) * 4] = aL[r];
        *(float*)&LDS[GT_OFF + kh * GT_KH + (row * 66 + c0 + 16) * 4] = aR[r];
      }
    __syncthreads();                                   // C
    // ---- P8: pointwise (R3 verbatim) ----
    float hn0, hn1;
    {
      const float* g0 = (const float*)&LDS[GT_OFF + (prow * 66) * 4];
      const float* g1 = (const float*)&LDS[GT_OFF + GT_KH + (prow * 66) * 4];
      const float gi = g0[colC] + g1[colC] + bi_i;
      const float gf = g0[16 + colC] + g1[16 + colC] + bi_f;
      const float gg = g0[32 + colC] + g1[32 + colC] + bi_g;
      const float go = g0[48 + colC] + g1[48 + colC] + bi_o;
      const float cn = sigf(gf) * creg0 + sigf(gi) * tanh_fast(gg);
      hn0 = sigf(go) * tanh_fast(cn);
      creg0 = cn;
    }
    {
      const float* g0 = (const float*)&LDS[GT_OFF + ((prow + 32) * 66) * 4];
      const float* g1 = (const float*)&LDS[GT_OFF + GT_KH + ((prow + 32) * 66) * 4];
      const float gi = g0[colC] + g1[colC] + bi_i;
      const float gf = g0[16 + colC] + g1[16 + colC] + bi_f;
      const float gg = g0[32 + colC] + g1[32 + colC] + bi_g;
      const float go = g0[48 + colC] + g1[48 + colC] + bi_o;
      const float cn = sigf(gf) * creg1 + sigf(gi) * tanh_fast(gg);
      hn1 = sigf(go) * tanh_fast(cn);
      creg1 = cn;
    }
    // ---- h hand-off: lane-pair packed 4B MALL stores ----
    const float o0 = __shfl_xor(hn0, 1);
    const float o1 = __shfl_xor(hn1, 1);
    if (!(tid & 1)) {
      unsigned short* hdst = hbuf + (((t + 1) & 1) ? (size_t)(NB * NH) : 0) +
                             (size_t)(bb0 + prow) * NH + jC;
      unsigned short* hdst2 = hdst + (size_t)32 * NH;
      const unsigned int d0 = cvtpk(hn0, o0);
      const unsigned int d1 = cvtpk(hn1, o1);
      asm volatile("global_store_dword %0, %1, off sc0 sc1" :: "v"(hdst), "v"(d0) : "memory");
      asm volatile("global_store_dword %0, %1, off sc0 sc1" :: "v"(hdst2), "v"(d1) : "memory");
    }
    asm volatile("s_waitcnt vmcnt(0)" ::: "memory");   // own h stores ACK'd at MALL
    __builtin_amdgcn_sched_barrier(0);
    if (lane == 0) atomicAdd(cptr, 1u);                // per-wave arrival
    // ---- off-critical-path: out1 + x prefetch for t+2 ----
    __builtin_nontemporal_store(hn0, &out1[((size_t)(bb0 + prow) * NT + t) * NH + jC]);
    __builtin_nontemporal_store(hn1, &out1[((size_t)(bb0 + 32 + prow) * NT + t) * NH + jC]);
    {
      const int tx = (t + 2 < NT) ? (t + 2) : (NT - 1);
      const float* xs = in + ((size_t)(bb0 + rA) * NT + tx) * ND + pA * 16;
#pragma unroll
      for (int i = 0; i < 4; ++i) xr4[i] = *(const floatx4*)(xs + 4 * i);
    }
  }
}

// ---------------------------------------------------------------------------
extern "C" void kernel_launch(void* const* d_in, const int* in_sizes, int n_in,
                              void* d_out, int out_size, void* d_ws, size_t ws_size,
                              hipStream_t stream) {
  (void)in_sizes; (void)n_in; (void)out_size; (void)ws_size;
  const float* in     = (const float*)d_in[0];
  const float* W_ih   = (const float*)d_in[1];
  const float* W_hh   = (const float*)d_in[2];
  const float* b_ih   = (const float*)d_in[3];
  const float* b_hh   = (const float*)d_in[4];
  const float* attn_W = (const float*)d_in[5];
  // d_in[6] (attn_b) cancels in the softmax -> unused.

  float* out0 = (float*)d_out;                          // (512,128,128)
  float* out1 = out0 + (size_t)NB * NT * ND;            // (512,128,512)

  float* attn_ws = (float*)d_ws;                                     // 256 KB
  unsigned short* hbuf = (unsigned short*)((char*)d_ws + 262144);    // 1 MB
  unsigned int* flags = (unsigned int*)((char*)d_ws + 262144 + 1048576); // 16 KB

  hipMemsetAsync(flags, 0, 16384, stream);
  attn_kernel<<<NB, 128, 0, stream>>>(in, attn_W, out0, attn_ws);
  rec_kernel<<<256, 512, 0, stream>>>(in, W_ih, W_hh, b_ih, b_hh, attn_ws,
                                      hbuf, flags, out1);
}

// Round 11
// 523.631 us; speedup vs baseline: 1.9260x; 1.9260x over previous
//
#include <hip/hip_runtime.h>

// B=512, T-1=128, D=128, H=512. softmax(proj_x + shift[:,None]) == softmax(proj_x)
// => attention is timestep-invariant; only the LSTM recurrence is sequential.
//
// R11 = R3 (552us, proven) + the three R10 components that its fatal sync
// drowned, with sync kept in R3's proven SHAPE:
//  (1) WT double-buffer; wi-MFMAs + wi-pack hoisted PRE-POLL (free work during
//      producer stagger); WT[t+1] write moved into the h-load shadow.
//  (2) barrier (d) removed: per-wave vmcnt(0) + lane0 atomicAdd to the BLOCK's
//      private counter line (8 atomics/step/block, 32 distinct lines/group —
//      no single-line contention, unlike R10). Wave0 polls 32 counters >= 8t
//      exactly like R3 polled 32 flags.
//  (3) v_cvt_pk_bf16_f32 packing.
// Geometry, staging, fragments, pointwise, MALL sc0 sc1 protocol = R3 verbatim.

typedef __attribute__((ext_vector_type(8))) short short8;
typedef __attribute__((ext_vector_type(4))) float floatx4;
typedef __attribute__((ext_vector_type(4))) unsigned int uintx4;

#define NB 512
#define NT 128
#define ND 128
#define NH 512

// LDS layout (132096 B; > 81920 => 1 block/CU)
#define HH_OFF 0          // h tile [64][512] bf16, swizzled (64 KB)
#define WT0_OFF 65536     // wi tile ping [64][128] bf16, swizzled (16 KB)
#define WT1_OFF 81920     // wi tile pong (16 KB)
#define GT_OFF 98304      // gates [2 kh][64][66] f32 (33792 B)
#define GT_KH  16896
#define LDS_BYTES 132096

static __device__ __forceinline__ unsigned short f2bf(float f) {
  unsigned int u = __float_as_uint(f);
  u += 0x7fffu + ((u >> 16) & 1u);   // RNE
  return (unsigned short)(u >> 16);
}
static __device__ __forceinline__ unsigned int cvtpk(float lo, float hi) {
  unsigned int r;
  asm("v_cvt_pk_bf16_f32 %0, %1, %2" : "=v"(r) : "v"(lo), "v"(hi));
  return r;
}
static __device__ __forceinline__ float sigf(float x) {
  return 1.f / (1.f + __expf(-x));
}
static __device__ __forceinline__ float tanh_fast(float x) {
  const float e = __expf(-2.f * fabsf(x));
  const float r = (1.f - e) / (1.f + e);
  return copysignf(r, x);
}

// ---------------------------------------------------------------------------
// Kernel A: attn[b,d] = softmax_d( sum_t in[b,t,d]*wx[t] ); out0 = attn*in
// ---------------------------------------------------------------------------
__global__ __launch_bounds__(128) void attn_kernel(
    const float* __restrict__ in, const float* __restrict__ attn_W,
    float* __restrict__ out0, float* __restrict__ attn_ws) {
  const int b = blockIdx.x;
  const int d = threadIdx.x;
  __shared__ float wx[NT];
  __shared__ float red[4];
  wx[d] = attn_W[2 * NH + d];
  __syncthreads();
  const float* ib = in + (size_t)b * (NT * ND);
  float p = 0.f;
#pragma unroll 8
  for (int t = 0; t < NT; ++t) p = fmaf(ib[t * ND + d], wx[t], p);
  float m = p;
#pragma unroll
  for (int off = 32; off >= 1; off >>= 1) m = fmaxf(m, __shfl_xor(m, off));
  const int wv = d >> 6;
  if ((d & 63) == 0) red[wv] = m;
  __syncthreads();
  const float M = fmaxf(red[0], red[1]);
  const float e = expf(p - M);
  float s = e;
#pragma unroll
  for (int off = 32; off >= 1; off >>= 1) s += __shfl_xor(s, off);
  if ((d & 63) == 0) red[2 + wv] = s;
  __syncthreads();
  const float a = e / (red[2] + red[3]);
  attn_ws[b * ND + d] = a;
#pragma unroll 4
  for (int t = 0; t < NT; ++t)
    out0[(size_t)b * (NT * ND) + t * ND + d] = a * ib[t * ND + d];
}

// ---------------------------------------------------------------------------
// Kernel C: persistent fused LSTM recurrence. 256 blocks x 512 thr, 1/CU.
// Block (gid=bid&7, sid=bid>>3): batch rows [gid*64,+64), h-cols [sid*16,+16).
// Wave wid: rw=wid&1 (row half), cg=(wid>>1)&1 (gate pair), kh=wid>>2 (K half).
// W fragments in registers (bh[8][2], bwi[2][2]); h + wi + gates in LDS.
// ---------------------------------------------------------------------------
__global__ __launch_bounds__(512, 2) void rec_kernel(
    const float* __restrict__ in, const float* __restrict__ W_ih,
    const float* __restrict__ W_hh, const float* __restrict__ b_ih,
    const float* __restrict__ b_hh, const float* __restrict__ attn_ws,
    unsigned short* __restrict__ hbuf, unsigned int* __restrict__ flags,
    float* __restrict__ out1) {
  __shared__ __align__(16) unsigned char LDS[LDS_BYTES];
  const int tid = threadIdx.x;
  const int bid = blockIdx.x;
  const int gid = bid & 7;
  const int sid = bid >> 3;
  const int bb0 = gid * 64;
  const int n0 = sid * 16;
  const int lane = tid & 63;
  const int wid = tid >> 6;
  const int rw = wid & 1;
  const int cg = (wid >> 1) & 1;
  const int kh = wid >> 2;
  const int colB = lane & 15;
  const int kg = lane >> 4;

  // --- W fragments -> registers (one-time), R3 verbatim ---
  short8 bh[8][2];
  short8 bwi[2][2];
#pragma unroll
  for (int j = 0; j < 2; ++j) {
    const int gate = cg * 2 + j;
    const float* wr_h = W_hh + (size_t)(gate * NH + n0 + colB) * NH;
    const float* wr_i = W_ih + (size_t)(gate * NH + n0 + colB) * ND;
#pragma unroll
    for (int ksl = 0; ksl < 8; ++ksl) {
      const int k0 = (kh * 8 + ksl) * 32 + kg * 8;
      floatx4 f0 = *(const floatx4*)(wr_h + k0);
      floatx4 f1 = *(const floatx4*)(wr_h + k0 + 4);
      short8 s;
#pragma unroll
      for (int i = 0; i < 4; ++i) {
        s[i] = (short)f2bf(f0[i]);
        s[4 + i] = (short)f2bf(f1[i]);
      }
      bh[ksl][j] = s;
    }
#pragma unroll
    for (int ksl = 0; ksl < 2; ++ksl) {
      const int k0 = (kh * 2 + ksl) * 32 + kg * 8;
      floatx4 f0 = *(const floatx4*)(wr_i + k0);
      floatx4 f1 = *(const floatx4*)(wr_i + k0 + 4);
      short8 s;
#pragma unroll
      for (int i = 0; i < 4; ++i) {
        s[i] = (short)f2bf(f0[i]);
        s[4 + i] = (short)f2bf(f1[i]);
      }
      bwi[ksl][j] = s;
    }
  }

  // --- attention weights (t-invariant) ---
  const int rA = tid >> 3;
  const int pA = tid & 7;
  float areg[16];
  {
    const float* ap = attn_ws + (bb0 + rA) * ND + pA * 16;
#pragma unroll
    for (int i = 0; i < 16; ++i) areg[i] = ap[i];
  }
  // --- biases ---
  const int colC = tid & 15;
  const int jC = n0 + colC;
  const float bi_i = b_ih[jC] + b_hh[jC];
  const float bi_f = b_ih[NH + jC] + b_hh[NH + jC];
  const float bi_g = b_ih[2 * NH + jC] + b_hh[2 * NH + jC];
  const float bi_o = b_ih[3 * NH + jC] + b_hh[3 * NH + jC];
  float creg0 = 0.f, creg1 = 0.f;

  const int rowa0 = rw * 32 + colB;
  const int rowa1 = rowa0 + 16;
  const int swa = (rowa0 & 7) << 4;
  const int prow = tid >> 4;
  unsigned int* cme = flags + (gid * 32 + sid) * 16;            // my counter
  const unsigned int* fpoll = flags + (gid * 32 + (lane & 31)) * 16;

  // --- prologue: WT0 <- wi_0; prefetch x_1 ---
  floatx4 xr4[4];
  {
    const float* xs = in + ((size_t)(bb0 + rA) * NT + 0) * ND + pA * 16;
#pragma unroll
    for (int i = 0; i < 4; ++i) xr4[i] = *(const floatx4*)(xs + 4 * i);
    unsigned int w[8];
#pragma unroll
    for (int i = 0; i < 8; ++i)
      w[i] = cvtpk(xr4[i >> 1][(i & 1) * 2 + 0] * areg[2 * i],
                   xr4[i >> 1][(i & 1) * 2 + 1] * areg[2 * i + 1]);
    const int base = WT0_OFF + rA * 256;
    const int swp = (rA & 7) << 4;
    uintx4 lo = {w[0], w[1], w[2], w[3]};
    uintx4 hi = {w[4], w[5], w[6], w[7]};
    *(uintx4*)&LDS[base + ((pA * 32) ^ swp)] = lo;
    *(uintx4*)&LDS[base + ((pA * 32 + 16) ^ swp)] = hi;
  }
  {
    const float* xs = in + ((size_t)(bb0 + rA) * NT + 1) * ND + pA * 16;
#pragma unroll
    for (int i = 0; i < 4; ++i) xr4[i] = *(const floatx4*)(xs + 4 * i);
  }
  __syncthreads();

  for (int t = 0; t < NT; ++t) {
    const int wtR = (t & 1) ? WT1_OFF : WT0_OFF;
    const int wtW = (t & 1) ? WT0_OFF : WT1_OFF;

    floatx4 acc00 = {0.f, 0.f, 0.f, 0.f};
    floatx4 acc01 = {0.f, 0.f, 0.f, 0.f};
    floatx4 acc10 = {0.f, 0.f, 0.f, 0.f};
    floatx4 acc11 = {0.f, 0.f, 0.f, 0.f};

    // ---- P1 (pre-poll): wi MFMAs from WT[t&1] + pack wi_{t+1} ----
#pragma unroll
    for (int ksl = 0; ksl < 2; ++ksl) {
      const int k2 = (kh * 2 + ksl) * 64 + kg * 16;
      short8 a0 = *(const short8*)&LDS[wtR + rowa0 * 256 + (k2 ^ swa)];
      short8 a1 = *(const short8*)&LDS[wtR + rowa1 * 256 + (k2 ^ swa)];
      acc00 = __builtin_amdgcn_mfma_f32_16x16x32_bf16(a0, bwi[ksl][0], acc00, 0, 0, 0);
      acc01 = __builtin_amdgcn_mfma_f32_16x16x32_bf16(a0, bwi[ksl][1], acc01, 0, 0, 0);
      acc10 = __builtin_amdgcn_mfma_f32_16x16x32_bf16(a1, bwi[ksl][0], acc10, 0, 0, 0);
      acc11 = __builtin_amdgcn_mfma_f32_16x16x32_bf16(a1, bwi[ksl][1], acc11, 0, 0, 0);
    }
    unsigned int w[8];
#pragma unroll
    for (int i = 0; i < 8; ++i)
      w[i] = cvtpk(xr4[i >> 1][(i & 1) * 2 + 0] * areg[2 * i],
                   xr4[i >> 1][(i & 1) * 2 + 1] * areg[2 * i + 1]);

    if (t > 0) {
      // ---- P2: group sync — wave0 polls 32 block-counters for >= 8t ----
      if (wid == 0) {
        const unsigned int target = (unsigned int)(t << 3);   // 8*t
        unsigned int v;
        do {
          asm volatile("global_load_dword %0, %1, off sc0 sc1\n\ts_waitcnt vmcnt(0)"
                       : "=v"(v) : "v"(fpoll) : "memory");
        } while (!__all(v >= target));
      }
      __syncthreads();                                   // (a)
      // ---- P3: issue full h-tile gather (1KB coalesced per load) ----
      const unsigned short* hsrc = hbuf + ((t & 1) ? (size_t)(NB * NH) : 0);
      uintx4 hq[8];
#pragma unroll
      for (int p = 0; p < 8; ++p) {
        const int idx = p * 512 + tid;
        const int r = idx >> 6, s = idx & 63;
        const unsigned short* src = hsrc + (size_t)(bb0 + r) * NH + s * 8;
        asm volatile("global_load_dwordx4 %0, %1, off sc0 sc1"
                     : "=v"(hq[p]) : "v"(src) : "memory");
      }
      // ---- shadow: WT[(t+1)&1] <- wi_{t+1} (dbuf => no barrier needed) ----
      {
        const int base = wtW + rA * 256;
        const int swp = (rA & 7) << 4;
        uintx4 lo = {w[0], w[1], w[2], w[3]};
        uintx4 hi = {w[4], w[5], w[6], w[7]};
        *(uintx4*)&LDS[base + ((pA * 32) ^ swp)] = lo;
        *(uintx4*)&LDS[base + ((pA * 32 + 16) ^ swp)] = hi;
      }
      asm volatile("s_waitcnt vmcnt(0)" ::: "memory");
      __builtin_amdgcn_sched_barrier(0);
      // ---- P4: HH stage ----
#pragma unroll
      for (int p = 0; p < 8; ++p) {
        const int idx = p * 512 + tid;
        const int r = idx >> 6, s = idx & 63;
        *(uintx4*)&LDS[HH_OFF + r * 1024 + ((s * 16) ^ ((r & 7) << 4))] = hq[p];
      }
      __syncthreads();                                   // (b)
      // ---- P5: h MFMAs ----
#pragma unroll
      for (int ksl = 0; ksl < 8; ++ksl) {
        const int k2 = (kh * 8 + ksl) * 64 + kg * 16;
        short8 a0 = *(const short8*)&LDS[HH_OFF + rowa0 * 1024 + (k2 ^ swa)];
        short8 a1 = *(const short8*)&LDS[HH_OFF + rowa1 * 1024 + (k2 ^ swa)];
        acc00 = __builtin_amdgcn_mfma_f32_16x16x32_bf16(a0, bh[ksl][0], acc00, 0, 0, 0);
        acc01 = __builtin_amdgcn_mfma_f32_16x16x32_bf16(a0, bh[ksl][1], acc01, 0, 0, 0);
        acc10 = __builtin_amdgcn_mfma_f32_16x16x32_bf16(a1, bh[ksl][0], acc10, 0, 0, 0);
        acc11 = __builtin_amdgcn_mfma_f32_16x16x32_bf16(a1, bh[ksl][1], acc11, 0, 0, 0);
      }
    } else {
      // t == 0: WT1 <- wi_1 (different buffer => safe without barrier)
      const int base = wtW + rA * 256;
      const int swp = (rA & 7) << 4;
      uintx4 lo = {w[0], w[1], w[2], w[3]};
      uintx4 hi = {w[4], w[5], w[6], w[7]};
      *(uintx4*)&LDS[base + ((pA * 32) ^ swp)] = lo;
      *(uintx4*)&LDS[base + ((pA * 32 + 16) ^ swp)] = hi;
    }
    // ---- P6: gate partials -> GT[kh][64][66] ----
#pragma unroll
    for (int i = 0; i < 2; ++i)
#pragma unroll
      for (int r = 0; r < 4; ++r) {
        const int row = rw * 32 + i * 16 + kg * 4 + r;
        const int c0 = cg * 32 + colB;
        const floatx4& aL = i ? acc10 : acc00;
        const floatx4& aR = i ? acc11 : acc01;
        *(float*)&LDS[GT_OFF + kh * GT_KH + (row * 66 + c0) * 4] = aL[r];
        *(float*)&LDS[GT_OFF + kh * GT_KH + (row * 66 + c0 + 16) * 4] = aR[r];
      }
    __syncthreads();                                     // (c)
    // ---- P7: pointwise (R3 verbatim) ----
    float hn0, hn1;
    {
      const float* g0 = (const float*)&LDS[GT_OFF + (prow * 66) * 4];
      const float* g1 = (const float*)&LDS[GT_OFF + GT_KH + (prow * 66) * 4];
      const float gi = g0[colC] + g1[colC] + bi_i;
      const float gf = g0[16 + colC] + g1[16 + colC] + bi_f;
      const float gg = g0[32 + colC] + g1[32 + colC] + bi_g;
      const float go = g0[48 + colC] + g1[48 + colC] + bi_o;
      const float cn = sigf(gf) * creg0 + sigf(gi) * tanh_fast(gg);
      hn0 = sigf(go) * tanh_fast(cn);
      creg0 = cn;
    }
    {
      const float* g0 = (const float*)&LDS[GT_OFF + ((prow + 32) * 66) * 4];
      const float* g1 = (const float*)&LDS[GT_OFF + GT_KH + ((prow + 32) * 66) * 4];
      const float gi = g0[colC] + g1[colC] + bi_i;
      const float gf = g0[16 + colC] + g1[16 + colC] + bi_f;
      const float gg = g0[32 + colC] + g1[32 + colC] + bi_g;
      const float go = g0[48 + colC] + g1[48 + colC] + bi_o;
      const float cn = sigf(gf) * creg1 + sigf(gi) * tanh_fast(gg);
      hn1 = sigf(go) * tanh_fast(cn);
      creg1 = cn;
    }
    // ---- h hand-off: lane-pair cvt_pk -> 4B MALL stores ----
    const float o0 = __shfl_xor(hn0, 1);
    const float o1 = __shfl_xor(hn1, 1);
    if (!(tid & 1)) {
      unsigned short* hdst = hbuf + (((t + 1) & 1) ? (size_t)(NB * NH) : 0) +
                             (size_t)(bb0 + prow) * NH + jC;
      unsigned short* hdst2 = hdst + (size_t)32 * NH;
      const unsigned int d0 = cvtpk(hn0, o0);
      const unsigned int d1 = cvtpk(hn1, o1);
      asm volatile("global_store_dword %0, %1, off sc0 sc1" :: "v"(hdst), "v"(d0) : "memory");
      asm volatile("global_store_dword %0, %1, off sc0 sc1" :: "v"(hdst2), "v"(d1) : "memory");
    }
    // ---- per-wave publish: own stores ACK'd -> +1 on block counter ----
    asm volatile("s_waitcnt vmcnt(0)" ::: "memory");
    if (lane == 0) atomicAdd(cme, 1u);
    // ---- off-critical-path: out1 + x prefetch for t+2 ----
    __builtin_nontemporal_store(hn0, &out1[((size_t)(bb0 + prow) * NT + t) * NH + jC]);
    __builtin_nontemporal_store(hn1, &out1[((size_t)(bb0 + 32 + prow) * NT + t) * NH + jC]);
    {
      const int tx = (t + 2 < NT) ? (t + 2) : (NT - 1);
      const float* xs = in + ((size_t)(bb0 + rA) * NT + tx) * ND + pA * 16;
#pragma unroll
      for (int i = 0; i < 4; ++i) xr4[i] = *(const floatx4*)(xs + 4 * i);
    }
  }
}

// ---------------------------------------------------------------------------
extern "C" void kernel_launch(void* const* d_in, const int* in_sizes, int n_in,
                              void* d_out, int out_size, void* d_ws, size_t ws_size,
                              hipStream_t stream) {
  (void)in_sizes; (void)n_in; (void)out_size; (void)ws_size;
  const float* in     = (const float*)d_in[0];
  const float* W_ih   = (const float*)d_in[1];
  const float* W_hh   = (const float*)d_in[2];
  const float* b_ih   = (const float*)d_in[3];
  const float* b_hh   = (const float*)d_in[4];
  const float* attn_W = (const float*)d_in[5];
  // d_in[6] (attn_b) cancels in the softmax -> unused.

  float* out0 = (float*)d_out;                          // (512,128,128)
  float* out1 = out0 + (size_t)NB * NT * ND;            // (512,128,512)

  float* attn_ws = (float*)d_ws;                                     // 256 KB
  unsigned short* hbuf = (unsigned short*)((char*)d_ws + 262144);    // 1 MB
  unsigned int* flags = (unsigned int*)((char*)d_ws + 262144 + 1048576); // 16 KB

  hipMemsetAsync(flags, 0, 16384, stream);
  attn_kernel<<<NB, 128, 0, stream>>>(in, attn_W, out0, attn_ws);
  rec_kernel<<<256, 512, 0, stream>>>(in, W_ih, W_hh, b_ih, b_hh, attn_ws,
                                      hbuf, flags, out1);
}

// Round 12
// 492.373 us; speedup vs baseline: 2.0482x; 1.0635x over previous
//
#include <hip/hip_runtime.h>

// B=512, T-1=128, D=128, H=512. softmax(proj_x + shift[:,None]) == softmax(proj_x)
// => attention is timestep-invariant; only the LSTM recurrence is sequential.
//
// R12 = R11 (532us, proven) with the GT gate-exchange rebuilt conflict-free:
//  - cell-major GT[kh][row][col][4 gates] (16B/cell), XOR swizzle (row&7)<<4
//  - writers: one ds_write_b64 per gate-pair (8 instead of 16 ops, round-clean)
//  - pointwise: one ds_read_b128 per cell per kh-plane (4 instead of 16 reads,
//    round-clean); gate bias folded into the kh=0 accumulator init.
// Old layout was row-stride 66 dwords ( ≡2 mod 32 ): 4-way read conflicts on
// low banks — the bulk of the 4.18e7 SQ_LDS_BANK_CONFLICT.
// Everything else (sync shape, geometry, staging, MALL sc0 sc1) = R11 verbatim.

typedef __attribute__((ext_vector_type(8))) short short8;
typedef __attribute__((ext_vector_type(4))) float floatx4;
typedef __attribute__((ext_vector_type(2))) float floatx2;
typedef __attribute__((ext_vector_type(4))) unsigned int uintx4;

#define NB 512
#define NT 128
#define ND 128
#define NH 512

// LDS layout (131072 B; > 81920 => 1 block/CU)
#define HH_OFF 0          // h tile [64][512] bf16, swizzled (64 KB)
#define WT0_OFF 65536     // wi tile ping [64][128] bf16, swizzled (16 KB)
#define WT1_OFF 81920     // wi tile pong (16 KB)
#define GT_OFF 98304      // gates [2 kh][64 rows][16 cols][4 gates] f32 (32 KB)
#define GT_PL  16384
#define LDS_BYTES 131072

static __device__ __forceinline__ unsigned short f2bf(float f) {
  unsigned int u = __float_as_uint(f);
  u += 0x7fffu + ((u >> 16) & 1u);   // RNE
  return (unsigned short)(u >> 16);
}
static __device__ __forceinline__ unsigned int cvtpk(float lo, float hi) {
  unsigned int r;
  asm("v_cvt_pk_bf16_f32 %0, %1, %2" : "=v"(r) : "v"(lo), "v"(hi));
  return r;
}
static __device__ __forceinline__ float sigf(float x) {
  return 1.f / (1.f + __expf(-x));
}
static __device__ __forceinline__ float tanh_fast(float x) {
  const float e = __expf(-2.f * fabsf(x));
  const float r = (1.f - e) / (1.f + e);
  return copysignf(r, x);
}

// ---------------------------------------------------------------------------
// Kernel A: attn[b,d] = softmax_d( sum_t in[b,t,d]*wx[t] ); out0 = attn*in
// ---------------------------------------------------------------------------
__global__ __launch_bounds__(128) void attn_kernel(
    const float* __restrict__ in, const float* __restrict__ attn_W,
    float* __restrict__ out0, float* __restrict__ attn_ws) {
  const int b = blockIdx.x;
  const int d = threadIdx.x;
  __shared__ float wx[NT];
  __shared__ float red[4];
  wx[d] = attn_W[2 * NH + d];
  __syncthreads();
  const float* ib = in + (size_t)b * (NT * ND);
  float p = 0.f;
#pragma unroll 8
  for (int t = 0; t < NT; ++t) p = fmaf(ib[t * ND + d], wx[t], p);
  float m = p;
#pragma unroll
  for (int off = 32; off >= 1; off >>= 1) m = fmaxf(m, __shfl_xor(m, off));
  const int wv = d >> 6;
  if ((d & 63) == 0) red[wv] = m;
  __syncthreads();
  const float M = fmaxf(red[0], red[1]);
  const float e = expf(p - M);
  float s = e;
#pragma unroll
  for (int off = 32; off >= 1; off >>= 1) s += __shfl_xor(s, off);
  if ((d & 63) == 0) red[2 + wv] = s;
  __syncthreads();
  const float a = e / (red[2] + red[3]);
  attn_ws[b * ND + d] = a;
#pragma unroll 4
  for (int t = 0; t < NT; ++t)
    out0[(size_t)b * (NT * ND) + t * ND + d] = a * ib[t * ND + d];
}

// ---------------------------------------------------------------------------
// Kernel C: persistent fused LSTM recurrence. 256 blocks x 512 thr, 1/CU.
// Block (gid=bid&7, sid=bid>>3): batch rows [gid*64,+64), h-cols [sid*16,+16).
// Wave wid: rw=wid&1 (row half), cg=(wid>>1)&1 (gate pair), kh=wid>>2 (K half).
// W fragments in registers (bh[8][2], bwi[2][2]); h + wi + gates in LDS.
// ---------------------------------------------------------------------------
__global__ __launch_bounds__(512, 2) void rec_kernel(
    const float* __restrict__ in, const float* __restrict__ W_ih,
    const float* __restrict__ W_hh, const float* __restrict__ b_ih,
    const float* __restrict__ b_hh, const float* __restrict__ attn_ws,
    unsigned short* __restrict__ hbuf, unsigned int* __restrict__ flags,
    float* __restrict__ out1) {
  __shared__ __align__(16) unsigned char LDS[LDS_BYTES];
  const int tid = threadIdx.x;
  const int bid = blockIdx.x;
  const int gid = bid & 7;
  const int sid = bid >> 3;
  const int bb0 = gid * 64;
  const int n0 = sid * 16;
  const int lane = tid & 63;
  const int wid = tid >> 6;
  const int rw = wid & 1;
  const int cg = (wid >> 1) & 1;
  const int kh = wid >> 2;
  const int colB = lane & 15;
  const int kg = lane >> 4;

  // --- W fragments -> registers (one-time), R11 verbatim ---
  short8 bh[8][2];
  short8 bwi[2][2];
#pragma unroll
  for (int j = 0; j < 2; ++j) {
    const int gate = cg * 2 + j;
    const float* wr_h = W_hh + (size_t)(gate * NH + n0 + colB) * NH;
    const float* wr_i = W_ih + (size_t)(gate * NH + n0 + colB) * ND;
#pragma unroll
    for (int ksl = 0; ksl < 8; ++ksl) {
      const int k0 = (kh * 8 + ksl) * 32 + kg * 8;
      floatx4 f0 = *(const floatx4*)(wr_h + k0);
      floatx4 f1 = *(const floatx4*)(wr_h + k0 + 4);
      short8 s;
#pragma unroll
      for (int i = 0; i < 4; ++i) {
        s[i] = (short)f2bf(f0[i]);
        s[4 + i] = (short)f2bf(f1[i]);
      }
      bh[ksl][j] = s;
    }
#pragma unroll
    for (int ksl = 0; ksl < 2; ++ksl) {
      const int k0 = (kh * 2 + ksl) * 32 + kg * 8;
      floatx4 f0 = *(const floatx4*)(wr_i + k0);
      floatx4 f1 = *(const floatx4*)(wr_i + k0 + 4);
      short8 s;
#pragma unroll
      for (int i = 0; i < 4; ++i) {
        s[i] = (short)f2bf(f0[i]);
        s[4 + i] = (short)f2bf(f1[i]);
      }
      bwi[ksl][j] = s;
    }
  }

  // --- attention weights (t-invariant) ---
  const int rA = tid >> 3;
  const int pA = tid & 7;
  float areg[16];
  {
    const float* ap = attn_ws + (bb0 + rA) * ND + pA * 16;
#pragma unroll
    for (int i = 0; i < 16; ++i) areg[i] = ap[i];
  }
  // --- per-wave gate biases (folded into kh=0 accumulator init) ---
  float bw0 = 0.f, bw1 = 0.f;
  if (kh == 0) {
    const int j0 = (cg * 2 + 0) * NH + n0 + colB;
    const int j1 = (cg * 2 + 1) * NH + n0 + colB;
    bw0 = b_ih[j0] + b_hh[j0];
    bw1 = b_ih[j1] + b_hh[j1];
  }
  const int colC = tid & 15;
  const int jC = n0 + colC;
  float creg0 = 0.f, creg1 = 0.f;

  const int rowa0 = rw * 32 + colB;
  const int rowa1 = rowa0 + 16;
  const int swa = (rowa0 & 7) << 4;
  const int prow = tid >> 4;
  unsigned int* cme = flags + (gid * 32 + sid) * 16;            // my counter
  const unsigned int* fpoll = flags + (gid * 32 + (lane & 31)) * 16;

  // --- prologue: WT0 <- wi_0; prefetch x_1 ---
  floatx4 xr4[4];
  {
    const float* xs = in + ((size_t)(bb0 + rA) * NT + 0) * ND + pA * 16;
#pragma unroll
    for (int i = 0; i < 4; ++i) xr4[i] = *(const floatx4*)(xs + 4 * i);
    unsigned int w[8];
#pragma unroll
    for (int i = 0; i < 8; ++i)
      w[i] = cvtpk(xr4[i >> 1][(i & 1) * 2 + 0] * areg[2 * i],
                   xr4[i >> 1][(i & 1) * 2 + 1] * areg[2 * i + 1]);
    const int base = WT0_OFF + rA * 256;
    const int swp = (rA & 7) << 4;
    uintx4 lo = {w[0], w[1], w[2], w[3]};
    uintx4 hi = {w[4], w[5], w[6], w[7]};
    *(uintx4*)&LDS[base + ((pA * 32) ^ swp)] = lo;
    *(uintx4*)&LDS[base + ((pA * 32 + 16) ^ swp)] = hi;
  }
  {
    const float* xs = in + ((size_t)(bb0 + rA) * NT + 1) * ND + pA * 16;
#pragma unroll
    for (int i = 0; i < 4; ++i) xr4[i] = *(const floatx4*)(xs + 4 * i);
  }
  __syncthreads();

  for (int t = 0; t < NT; ++t) {
    const int wtR = (t & 1) ? WT1_OFF : WT0_OFF;
    const int wtW = (t & 1) ? WT0_OFF : WT1_OFF;

    floatx4 acc00 = {bw0, bw0, bw0, bw0};
    floatx4 acc01 = {bw1, bw1, bw1, bw1};
    floatx4 acc10 = {bw0, bw0, bw0, bw0};
    floatx4 acc11 = {bw1, bw1, bw1, bw1};

    // ---- P1 (pre-poll): wi MFMAs from WT[t&1] + pack wi_{t+1} ----
#pragma unroll
    for (int ksl = 0; ksl < 2; ++ksl) {
      const int k2 = (kh * 2 + ksl) * 64 + kg * 16;
      short8 a0 = *(const short8*)&LDS[wtR + rowa0 * 256 + (k2 ^ swa)];
      short8 a1 = *(const short8*)&LDS[wtR + rowa1 * 256 + (k2 ^ swa)];
      acc00 = __builtin_amdgcn_mfma_f32_16x16x32_bf16(a0, bwi[ksl][0], acc00, 0, 0, 0);
      acc01 = __builtin_amdgcn_mfma_f32_16x16x32_bf16(a0, bwi[ksl][1], acc01, 0, 0, 0);
      acc10 = __builtin_amdgcn_mfma_f32_16x16x32_bf16(a1, bwi[ksl][0], acc10, 0, 0, 0);
      acc11 = __builtin_amdgcn_mfma_f32_16x16x32_bf16(a1, bwi[ksl][1], acc11, 0, 0, 0);
    }
    unsigned int w[8];
#pragma unroll
    for (int i = 0; i < 8; ++i)
      w[i] = cvtpk(xr4[i >> 1][(i & 1) * 2 + 0] * areg[2 * i],
                   xr4[i >> 1][(i & 1) * 2 + 1] * areg[2 * i + 1]);

    if (t > 0) {
      // ---- P2: group sync — wave0 polls 32 block-counters for >= 8t ----
      if (wid == 0) {
        const unsigned int target = (unsigned int)(t << 3);   // 8*t
        unsigned int v;
        do {
          asm volatile("global_load_dword %0, %1, off sc0 sc1\n\ts_waitcnt vmcnt(0)"
                       : "=v"(v) : "v"(fpoll) : "memory");
        } while (!__all(v >= target));
      }
      __syncthreads();                                   // (a)
      // ---- P3: issue full h-tile gather (1KB coalesced per load) ----
      const unsigned short* hsrc = hbuf + ((t & 1) ? (size_t)(NB * NH) : 0);
      uintx4 hq[8];
#pragma unroll
      for (int p = 0; p < 8; ++p) {
        const int idx = p * 512 + tid;
        const int r = idx >> 6, s = idx & 63;
        const unsigned short* src = hsrc + (size_t)(bb0 + r) * NH + s * 8;
        asm volatile("global_load_dwordx4 %0, %1, off sc0 sc1"
                     : "=v"(hq[p]) : "v"(src) : "memory");
      }
      // ---- shadow: WT[(t+1)&1] <- wi_{t+1} (dbuf => no barrier needed) ----
      {
        const int base = wtW + rA * 256;
        const int swp = (rA & 7) << 4;
        uintx4 lo = {w[0], w[1], w[2], w[3]};
        uintx4 hi = {w[4], w[5], w[6], w[7]};
        *(uintx4*)&LDS[base + ((pA * 32) ^ swp)] = lo;
        *(uintx4*)&LDS[base + ((pA * 32 + 16) ^ swp)] = hi;
      }
      asm volatile("s_waitcnt vmcnt(0)" ::: "memory");
      __builtin_amdgcn_sched_barrier(0);
      // ---- P4: HH stage ----
#pragma unroll
      for (int p = 0; p < 8; ++p) {
        const int idx = p * 512 + tid;
        const int r = idx >> 6, s = idx & 63;
        *(uintx4*)&LDS[HH_OFF + r * 1024 + ((s * 16) ^ ((r & 7) << 4))] = hq[p];
      }
      __syncthreads();                                   // (b)
      // ---- P5: h MFMAs ----
#pragma unroll
      for (int ksl = 0; ksl < 8; ++ksl) {
        const int k2 = (kh * 8 + ksl) * 64 + kg * 16;
        short8 a0 = *(const short8*)&LDS[HH_OFF + rowa0 * 1024 + (k2 ^ swa)];
        short8 a1 = *(const short8*)&LDS[HH_OFF + rowa1 * 1024 + (k2 ^ swa)];
        acc00 = __builtin_amdgcn_mfma_f32_16x16x32_bf16(a0, bh[ksl][0], acc00, 0, 0, 0);
        acc01 = __builtin_amdgcn_mfma_f32_16x16x32_bf16(a0, bh[ksl][1], acc01, 0, 0, 0);
        acc10 = __builtin_amdgcn_mfma_f32_16x16x32_bf16(a1, bh[ksl][0], acc10, 0, 0, 0);
        acc11 = __builtin_amdgcn_mfma_f32_16x16x32_bf16(a1, bh[ksl][1], acc11, 0, 0, 0);
      }
    } else {
      // t == 0: WT1 <- wi_1 (different buffer => safe without barrier)
      const int base = wtW + rA * 256;
      const int swp = (rA & 7) << 4;
      uintx4 lo = {w[0], w[1], w[2], w[3]};
      uintx4 hi = {w[4], w[5], w[6], w[7]};
      *(uintx4*)&LDS[base + ((pA * 32) ^ swp)] = lo;
      *(uintx4*)&LDS[base + ((pA * 32 + 16) ^ swp)] = hi;
    }
    // ---- P6: gate pairs -> GT[kh][row][col][4] (cell-major, b64 writes) ----
#pragma unroll
    for (int i = 0; i < 2; ++i)
#pragma unroll
      for (int r = 0; r < 4; ++r) {
        const int row = rw * 32 + i * 16 + kg * 4 + r;
        const int sw = ((kg * 4 + r) & 7) << 4;
        floatx2 v;
        v[0] = i ? acc10[r] : acc00[r];
        v[1] = i ? acc11[r] : acc01[r];
        *(floatx2*)&LDS[GT_OFF + kh * GT_PL + row * 256 +
                        ((colB * 16 + cg * 8) ^ sw)] = v;
      }
    __syncthreads();                                     // (c)
    // ---- P7: pointwise — one b128 per cell per plane ----
    float hn0, hn1;
    {
      const int pw0 = prow * 256 + ((colC * 16) ^ ((prow & 7) << 4));
      const int pw1 = pw0 + 32 * 256;                    // (prow+32)&7 == prow&7
      floatx4 gA = *(const floatx4*)&LDS[GT_OFF + pw0];
      floatx4 gB = *(const floatx4*)&LDS[GT_OFF + GT_PL + pw0];
      const float gi = gA[0] + gB[0];
      const float gf = gA[1] + gB[1];
      const float gg = gA[2] + gB[2];
      const float go = gA[3] + gB[3];
      const float cn = sigf(gf) * creg0 + sigf(gi) * tanh_fast(gg);
      hn0 = sigf(go) * tanh_fast(cn);
      creg0 = cn;
      floatx4 gC = *(const floatx4*)&LDS[GT_OFF + pw1];
      floatx4 gD = *(const floatx4*)&LDS[GT_OFF + GT_PL + pw1];
      const float gi1 = gC[0] + gD[0];
      const float gf1 = gC[1] + gD[1];
      const float gg1 = gC[2] + gD[2];
      const float go1 = gC[3] + gD[3];
      const float cn1 = sigf(gf1) * creg1 + sigf(gi1) * tanh_fast(gg1);
      hn1 = sigf(go1) * tanh_fast(cn1);
      creg1 = cn1;
    }
    // ---- h hand-off: lane-pair cvt_pk -> 4B MALL stores ----
    const float o0 = __shfl_xor(hn0, 1);
    const float o1 = __shfl_xor(hn1, 1);
    if (!(tid & 1)) {
      unsigned short* hdst = hbuf + (((t + 1) & 1) ? (size_t)(NB * NH) : 0) +
                             (size_t)(bb0 + prow) * NH + jC;
      unsigned short* hdst2 = hdst + (size_t)32 * NH;
      const unsigned int d0 = cvtpk(hn0, o0);
      const unsigned int d1 = cvtpk(hn1, o1);
      asm volatile("global_store_dword %0, %1, off sc0 sc1" :: "v"(hdst), "v"(d0) : "memory");
      asm volatile("global_store_dword %0, %1, off sc0 sc1" :: "v"(hdst2), "v"(d1) : "memory");
    }
    // ---- per-wave publish: own stores ACK'd -> +1 on block counter ----
    asm volatile("s_waitcnt vmcnt(0)" ::: "memory");
    if (lane == 0) atomicAdd(cme, 1u);
    // ---- off-critical-path: out1 + x prefetch for t+2 ----
    __builtin_nontemporal_store(hn0, &out1[((size_t)(bb0 + prow) * NT + t) * NH + jC]);
    __builtin_nontemporal_store(hn1, &out1[((size_t)(bb0 + 32 + prow) * NT + t) * NH + jC]);
    {
      const int tx = (t + 2 < NT) ? (t + 2) : (NT - 1);
      const float* xs = in + ((size_t)(bb0 + rA) * NT + tx) * ND + pA * 16;
#pragma unroll
      for (int i = 0; i < 4; ++i) xr4[i] = *(const floatx4*)(xs + 4 * i);
    }
  }
}

// ---------------------------------------------------------------------------
extern "C" void kernel_launch(void* const* d_in, const int* in_sizes, int n_in,
                              void* d_out, int out_size, void* d_ws, size_t ws_size,
                              hipStream_t stream) {
  (void)in_sizes; (void)n_in; (void)out_size; (void)ws_size;
  const float* in     = (const float*)d_in[0];
  const float* W_ih   = (const float*)d_in[1];
  const float* W_hh   = (const float*)d_in[2];
  const float* b_ih   = (const float*)d_in[3];
  const float* b_hh   = (const float*)d_in[4];
  const float* attn_W = (const float*)d_in[5];
  // d_in[6] (attn_b) cancels in the softmax -> unused.

  float* out0 = (float*)d_out;                          // (512,128,128)
  float* out1 = out0 + (size_t)NB * NT * ND;            // (512,128,512)

  float* attn_ws = (float*)d_ws;                                     // 256 KB
  unsigned short* hbuf = (unsigned short*)((char*)d_ws + 262144);    // 1 MB
  unsigned int* flags = (unsigned int*)((char*)d_ws + 262144 + 1048576); // 16 KB

  hipMemsetAsync(flags, 0, 16384, stream);
  attn_kernel<<<NB, 128, 0, stream>>>(in, attn_W, out0, attn_ws);
  rec_kernel<<<256, 512, 0, stream>>>(in, W_ih, W_hh, b_ih, b_hh, attn_ws,
                                      hbuf, flags, out1);
}

// Round 14
// 464.457 us; speedup vs baseline: 2.1714x; 1.0601x over previous
//
#include <hip/hip_runtime.h>

// B=512, T-1=128, D=128, H=512. softmax(proj_x + shift[:,None]) == softmax(proj_x)
// => attention is timestep-invariant; only the LSTM recurrence is sequential.
//
// R14 = R12 (509us, proven flag protocol) + three low-risk deltas:
//  (1) barrier (a) removed: ALL waves poll the 32 per-block arrival counters.
//      Sound because poll target 8t includes MY OWN block's 8 wave-arrivals =>
//      no wave passes until every sibling finished GT-read/publish of t-1
//      (GT/HH hazards covered; WT already double-buffered). No shared-line
//      atomics (R10's failure mode), polls spread over 32 lines.
//  (2) v_rcp_f32 for pointwise divisions (no fast-math => each '/' was a
//      ~8-op div sequence; 10 divisions/thread/step on the critical path).
//  (3) out1 stores packed to 8B via the existing lane-pair shuffles.
// R13's sentinel-fused sync FAILED correctness (stale h) — flags only.

typedef __attribute__((ext_vector_type(8))) short short8;
typedef __attribute__((ext_vector_type(4))) float floatx4;
typedef __attribute__((ext_vector_type(2))) float floatx2;
typedef __attribute__((ext_vector_type(4))) unsigned int uintx4;

#define NB 512
#define NT 128
#define ND 128
#define NH 512

// LDS layout (131072 B; > 81920 => 1 block/CU)
#define HH_OFF 0          // h tile [64][512] bf16, swizzled (64 KB)
#define WT0_OFF 65536     // wi tile ping [64][128] bf16, swizzled (16 KB)
#define WT1_OFF 81920     // wi tile pong (16 KB)
#define GT_OFF 98304      // gates [2 kh][64 rows][16 cols][4 gates] f32 (32 KB)
#define GT_PL  16384
#define LDS_BYTES 131072

static __device__ __forceinline__ unsigned short f2bf(float f) {
  unsigned int u = __float_as_uint(f);
  u += 0x7fffu + ((u >> 16) & 1u);   // RNE
  return (unsigned short)(u >> 16);
}
static __device__ __forceinline__ unsigned int cvtpk(float lo, float hi) {
  unsigned int r;
  asm("v_cvt_pk_bf16_f32 %0, %1, %2" : "=v"(r) : "v"(lo), "v"(hi));
  return r;
}
static __device__ __forceinline__ float rcpf(float x) {
  float r;
  asm("v_rcp_f32 %0, %1" : "=v"(r) : "v"(x));
  return r;
}
static __device__ __forceinline__ float sigf(float x) {
  return rcpf(1.f + __expf(-x));
}
static __device__ __forceinline__ float tanh_fast(float x) {
  const float e = __expf(-2.f * fabsf(x));
  const float r = (1.f - e) * rcpf(1.f + e);
  return copysignf(r, x);
}

// ---------------------------------------------------------------------------
// Kernel A: attn[b,d] = softmax_d( sum_t in[b,t,d]*wx[t] ); out0 = attn*in
// ---------------------------------------------------------------------------
__global__ __launch_bounds__(128) void attn_kernel(
    const float* __restrict__ in, const float* __restrict__ attn_W,
    float* __restrict__ out0, float* __restrict__ attn_ws) {
  const int b = blockIdx.x;
  const int d = threadIdx.x;
  __shared__ float wx[NT];
  __shared__ float red[4];
  wx[d] = attn_W[2 * NH + d];
  __syncthreads();
  const float* ib = in + (size_t)b * (NT * ND);
  float p = 0.f;
#pragma unroll 8
  for (int t = 0; t < NT; ++t) p = fmaf(ib[t * ND + d], wx[t], p);
  float m = p;
#pragma unroll
  for (int off = 32; off >= 1; off >>= 1) m = fmaxf(m, __shfl_xor(m, off));
  const int wv = d >> 6;
  if ((d & 63) == 0) red[wv] = m;
  __syncthreads();
  const float M = fmaxf(red[0], red[1]);
  const float e = expf(p - M);
  float s = e;
#pragma unroll
  for (int off = 32; off >= 1; off >>= 1) s += __shfl_xor(s, off);
  if ((d & 63) == 0) red[2 + wv] = s;
  __syncthreads();
  const float a = e / (red[2] + red[3]);
  attn_ws[b * ND + d] = a;
#pragma unroll 4
  for (int t = 0; t < NT; ++t)
    out0[(size_t)b * (NT * ND) + t * ND + d] = a * ib[t * ND + d];
}

// ---------------------------------------------------------------------------
// Kernel C: persistent fused LSTM recurrence. 256 blocks x 512 thr, 1/CU.
// Block (gid=bid&7, sid=bid>>3): batch rows [gid*64,+64), h-cols [sid*16,+16).
// Wave wid: rw=wid&1 (row half), cg=(wid>>1)&1 (gate pair), kh=wid>>2 (K half).
// W fragments in registers (bh[8][2], bwi[2][2]); h + wi + gates in LDS.
// ---------------------------------------------------------------------------
__global__ __launch_bounds__(512, 2) void rec_kernel(
    const float* __restrict__ in, const float* __restrict__ W_ih,
    const float* __restrict__ W_hh, const float* __restrict__ b_ih,
    const float* __restrict__ b_hh, const float* __restrict__ attn_ws,
    unsigned short* __restrict__ hbuf, unsigned int* __restrict__ flags,
    float* __restrict__ out1) {
  __shared__ __align__(16) unsigned char LDS[LDS_BYTES];
  const int tid = threadIdx.x;
  const int bid = blockIdx.x;
  const int gid = bid & 7;
  const int sid = bid >> 3;
  const int bb0 = gid * 64;
  const int n0 = sid * 16;
  const int lane = tid & 63;
  const int wid = tid >> 6;
  const int rw = wid & 1;
  const int cg = (wid >> 1) & 1;
  const int kh = wid >> 2;
  const int colB = lane & 15;
  const int kg = lane >> 4;

  // --- W fragments -> registers (one-time), R12 verbatim ---
  short8 bh[8][2];
  short8 bwi[2][2];
#pragma unroll
  for (int j = 0; j < 2; ++j) {
    const int gate = cg * 2 + j;
    const float* wr_h = W_hh + (size_t)(gate * NH + n0 + colB) * NH;
    const float* wr_i = W_ih + (size_t)(gate * NH + n0 + colB) * ND;
#pragma unroll
    for (int ksl = 0; ksl < 8; ++ksl) {
      const int k0 = (kh * 8 + ksl) * 32 + kg * 8;
      floatx4 f0 = *(const floatx4*)(wr_h + k0);
      floatx4 f1 = *(const floatx4*)(wr_h + k0 + 4);
      short8 s;
#pragma unroll
      for (int i = 0; i < 4; ++i) {
        s[i] = (short)f2bf(f0[i]);
        s[4 + i] = (short)f2bf(f1[i]);
      }
      bh[ksl][j] = s;
    }
#pragma unroll
    for (int ksl = 0; ksl < 2; ++ksl) {
      const int k0 = (kh * 2 + ksl) * 32 + kg * 8;
      floatx4 f0 = *(const floatx4*)(wr_i + k0);
      floatx4 f1 = *(const floatx4*)(wr_i + k0 + 4);
      short8 s;
#pragma unroll
      for (int i = 0; i < 4; ++i) {
        s[i] = (short)f2bf(f0[i]);
        s[4 + i] = (short)f2bf(f1[i]);
      }
      bwi[ksl][j] = s;
    }
  }

  // --- attention weights (t-invariant) ---
  const int rA = tid >> 3;
  const int pA = tid & 7;
  float areg[16];
  {
    const float* ap = attn_ws + (bb0 + rA) * ND + pA * 16;
#pragma unroll
    for (int i = 0; i < 16; ++i) areg[i] = ap[i];
  }
  // --- per-wave gate biases (folded into kh=0 accumulator init) ---
  float bw0 = 0.f, bw1 = 0.f;
  if (kh == 0) {
    const int j0 = (cg * 2 + 0) * NH + n0 + colB;
    const int j1 = (cg * 2 + 1) * NH + n0 + colB;
    bw0 = b_ih[j0] + b_hh[j0];
    bw1 = b_ih[j1] + b_hh[j1];
  }
  const int colC = tid & 15;
  const int jC = n0 + colC;
  float creg0 = 0.f, creg1 = 0.f;

  const int rowa0 = rw * 32 + colB;
  const int rowa1 = rowa0 + 16;
  const int swa = (rowa0 & 7) << 4;
  const int prow = tid >> 4;
  unsigned int* cme = flags + (gid * 32 + sid) * 16;            // my counter
  const unsigned int* fpoll = flags + (gid * 32 + (lane & 31)) * 16;

  // --- prologue: WT0 <- wi_0; prefetch x_1 ---
  floatx4 xr4[4];
  {
    const float* xs = in + ((size_t)(bb0 + rA) * NT + 0) * ND + pA * 16;
#pragma unroll
    for (int i = 0; i < 4; ++i) xr4[i] = *(const floatx4*)(xs + 4 * i);
    unsigned int w[8];
#pragma unroll
    for (int i = 0; i < 8; ++i)
      w[i] = cvtpk(xr4[i >> 1][(i & 1) * 2 + 0] * areg[2 * i],
                   xr4[i >> 1][(i & 1) * 2 + 1] * areg[2 * i + 1]);
    const int base = WT0_OFF + rA * 256;
    const int swp = (rA & 7) << 4;
    uintx4 lo = {w[0], w[1], w[2], w[3]};
    uintx4 hi = {w[4], w[5], w[6], w[7]};
    *(uintx4*)&LDS[base + ((pA * 32) ^ swp)] = lo;
    *(uintx4*)&LDS[base + ((pA * 32 + 16) ^ swp)] = hi;
  }
  {
    const float* xs = in + ((size_t)(bb0 + rA) * NT + 1) * ND + pA * 16;
#pragma unroll
    for (int i = 0; i < 4; ++i) xr4[i] = *(const floatx4*)(xs + 4 * i);
  }
  __syncthreads();

  for (int t = 0; t < NT; ++t) {
    const int wtR = (t & 1) ? WT1_OFF : WT0_OFF;
    const int wtW = (t & 1) ? WT0_OFF : WT1_OFF;

    floatx4 acc00 = {bw0, bw0, bw0, bw0};
    floatx4 acc01 = {bw1, bw1, bw1, bw1};
    floatx4 acc10 = {bw0, bw0, bw0, bw0};
    floatx4 acc11 = {bw1, bw1, bw1, bw1};

    // ---- P1 (pre-poll): wi MFMAs from WT[t&1] + pack wi_{t+1} ----
#pragma unroll
    for (int ksl = 0; ksl < 2; ++ksl) {
      const int k2 = (kh * 2 + ksl) * 64 + kg * 16;
      short8 a0 = *(const short8*)&LDS[wtR + rowa0 * 256 + (k2 ^ swa)];
      short8 a1 = *(const short8*)&LDS[wtR + rowa1 * 256 + (k2 ^ swa)];
      acc00 = __builtin_amdgcn_mfma_f32_16x16x32_bf16(a0, bwi[ksl][0], acc00, 0, 0, 0);
      acc01 = __builtin_amdgcn_mfma_f32_16x16x32_bf16(a0, bwi[ksl][1], acc01, 0, 0, 0);
      acc10 = __builtin_amdgcn_mfma_f32_16x16x32_bf16(a1, bwi[ksl][0], acc10, 0, 0, 0);
      acc11 = __builtin_amdgcn_mfma_f32_16x16x32_bf16(a1, bwi[ksl][1], acc11, 0, 0, 0);
    }
    unsigned int w[8];
#pragma unroll
    for (int i = 0; i < 8; ++i)
      w[i] = cvtpk(xr4[i >> 1][(i & 1) * 2 + 0] * areg[2 * i],
                   xr4[i >> 1][(i & 1) * 2 + 1] * areg[2 * i + 1]);

    if (t > 0) {
      // ---- P2: ALL waves poll the 32 block-counters for >= 8t.
      //      Poll subsumes barrier (a): target includes my own block's 8
      //      wave-arrivals => all sibling waves passed publish of t-1. ----
      {
        const unsigned int target = (unsigned int)(t << 3);   // 8*t
        unsigned int v;
        do {
          asm volatile("global_load_dword %0, %1, off sc0 sc1\n\ts_waitcnt vmcnt(0)"
                       : "=v"(v) : "v"(fpoll) : "memory");
        } while (!__all(v >= target));
      }
      // ---- P3: issue full h-tile gather (1KB coalesced per load) ----
      const unsigned short* hsrc = hbuf + ((t & 1) ? (size_t)(NB * NH) : 0);
      uintx4 hq[8];
#pragma unroll
      for (int p = 0; p < 8; ++p) {
        const int idx = p * 512 + tid;
        const int r = idx >> 6, s = idx & 63;
        const unsigned short* src = hsrc + (size_t)(bb0 + r) * NH + s * 8;
        asm volatile("global_load_dwordx4 %0, %1, off sc0 sc1"
                     : "=v"(hq[p]) : "v"(src) : "memory");
      }
      // ---- shadow: WT[(t+1)&1] <- wi_{t+1} (dbuf => no barrier needed) ----
      {
        const int base = wtW + rA * 256;
        const int swp = (rA & 7) << 4;
        uintx4 lo = {w[0], w[1], w[2], w[3]};
        uintx4 hi = {w[4], w[5], w[6], w[7]};
        *(uintx4*)&LDS[base + ((pA * 32) ^ swp)] = lo;
        *(uintx4*)&LDS[base + ((pA * 32 + 16) ^ swp)] = hi;
      }
      asm volatile("s_waitcnt vmcnt(0)" ::: "memory");
      __builtin_amdgcn_sched_barrier(0);
      // ---- P4: HH stage ----
#pragma unroll
      for (int p = 0; p < 8; ++p) {
        const int idx = p * 512 + tid;
        const int r = idx >> 6, s = idx & 63;
        *(uintx4*)&LDS[HH_OFF + r * 1024 + ((s * 16) ^ ((r & 7) << 4))] = hq[p];
      }
      __syncthreads();                                   // (b)
      // ---- P5: h MFMAs ----
#pragma unroll
      for (int ksl = 0; ksl < 8; ++ksl) {
        const int k2 = (kh * 8 + ksl) * 64 + kg * 16;
        short8 a0 = *(const short8*)&LDS[HH_OFF + rowa0 * 1024 + (k2 ^ swa)];
        short8 a1 = *(const short8*)&LDS[HH_OFF + rowa1 * 1024 + (k2 ^ swa)];
        acc00 = __builtin_amdgcn_mfma_f32_16x16x32_bf16(a0, bh[ksl][0], acc00, 0, 0, 0);
        acc01 = __builtin_amdgcn_mfma_f32_16x16x32_bf16(a0, bh[ksl][1], acc01, 0, 0, 0);
        acc10 = __builtin_amdgcn_mfma_f32_16x16x32_bf16(a1, bh[ksl][0], acc10, 0, 0, 0);
        acc11 = __builtin_amdgcn_mfma_f32_16x16x32_bf16(a1, bh[ksl][1], acc11, 0, 0, 0);
      }
    } else {
      // t == 0: WT1 <- wi_1 (different buffer => safe without barrier)
      const int base = wtW + rA * 256;
      const int swp = (rA & 7) << 4;
      uintx4 lo = {w[0], w[1], w[2], w[3]};
      uintx4 hi = {w[4], w[5], w[6], w[7]};
      *(uintx4*)&LDS[base + ((pA * 32) ^ swp)] = lo;
      *(uintx4*)&LDS[base + ((pA * 32 + 16) ^ swp)] = hi;
    }
    // ---- P6: gate pairs -> GT[kh][row][col][4] (cell-major, b64 writes) ----
#pragma unroll
    for (int i = 0; i < 2; ++i)
#pragma unroll
      for (int r = 0; r < 4; ++r) {
        const int row = rw * 32 + i * 16 + kg * 4 + r;
        const int sw = ((kg * 4 + r) & 7) << 4;
        floatx2 v;
        v[0] = i ? acc10[r] : acc00[r];
        v[1] = i ? acc11[r] : acc01[r];
        *(floatx2*)&LDS[GT_OFF + kh * GT_PL + row * 256 +
                        ((colB * 16 + cg * 8) ^ sw)] = v;
      }
    __syncthreads();                                     // (c)
    // ---- P7: pointwise — one b128 per cell per plane, fast rcp ----
    float hn0, hn1;
    {
      const int pw0 = prow * 256 + ((colC * 16) ^ ((prow & 7) << 4));
      const int pw1 = pw0 + 32 * 256;                    // (prow+32)&7 == prow&7
      floatx4 gA = *(const floatx4*)&LDS[GT_OFF + pw0];
      floatx4 gB = *(const floatx4*)&LDS[GT_OFF + GT_PL + pw0];
      const float gi = gA[0] + gB[0];
      const float gf = gA[1] + gB[1];
      const float gg = gA[2] + gB[2];
      const float go = gA[3] + gB[3];
      const float cn = sigf(gf) * creg0 + sigf(gi) * tanh_fast(gg);
      hn0 = sigf(go) * tanh_fast(cn);
      creg0 = cn;
      floatx4 gC = *(const floatx4*)&LDS[GT_OFF + pw1];
      floatx4 gD = *(const floatx4*)&LDS[GT_OFF + GT_PL + pw1];
      const float gi1 = gC[0] + gD[0];
      const float gf1 = gC[1] + gD[1];
      const float gg1 = gC[2] + gD[2];
      const float go1 = gC[3] + gD[3];
      const float cn1 = sigf(gf1) * creg1 + sigf(gi1) * tanh_fast(gg1);
      hn1 = sigf(go1) * tanh_fast(cn1);
      creg1 = cn1;
    }
    // ---- h hand-off: lane-pair cvt_pk -> 4B MALL stores ----
    const float o0 = __shfl_xor(hn0, 1);
    const float o1 = __shfl_xor(hn1, 1);
    if (!(tid & 1)) {
      unsigned short* hdst = hbuf + (((t + 1) & 1) ? (size_t)(NB * NH) : 0) +
                             (size_t)(bb0 + prow) * NH + jC;
      unsigned short* hdst2 = hdst + (size_t)32 * NH;
      const unsigned int d0 = cvtpk(hn0, o0);
      const unsigned int d1 = cvtpk(hn1, o1);
      asm volatile("global_store_dword %0, %1, off sc0 sc1" :: "v"(hdst), "v"(d0) : "memory");
      asm volatile("global_store_dword %0, %1, off sc0 sc1" :: "v"(hdst2), "v"(d1) : "memory");
    }
    // ---- per-wave publish: own stores ACK'd -> +1 on block counter ----
    asm volatile("s_waitcnt vmcnt(0)" ::: "memory");
    if (lane == 0) atomicAdd(cme, 1u);
    // ---- off-critical-path: out1 (8B lane-pair packed) + x prefetch ----
    if (!(tid & 1)) {
      floatx2 v0 = {hn0, o0};
      floatx2 v1 = {hn1, o1};
      __builtin_nontemporal_store(v0,
          (floatx2*)&out1[((size_t)(bb0 + prow) * NT + t) * NH + jC]);
      __builtin_nontemporal_store(v1,
          (floatx2*)&out1[((size_t)(bb0 + 32 + prow) * NT + t) * NH + jC]);
    }
    {
      const int tx = (t + 2 < NT) ? (t + 2) : (NT - 1);
      const float* xs = in + ((size_t)(bb0 + rA) * NT + tx) * ND + pA * 16;
#pragma unroll
      for (int i = 0; i < 4; ++i) xr4[i] = *(const floatx4*)(xs + 4 * i);
    }
  }
}

// ---------------------------------------------------------------------------
extern "C" void kernel_launch(void* const* d_in, const int* in_sizes, int n_in,
                              void* d_out, int out_size, void* d_ws, size_t ws_size,
                              hipStream_t stream) {
  (void)in_sizes; (void)n_in; (void)out_size; (void)ws_size;
  const float* in     = (const float*)d_in[0];
  const float* W_ih   = (const float*)d_in[1];
  const float* W_hh   = (const float*)d_in[2];
  const float* b_ih   = (const float*)d_in[3];
  const float* b_hh   = (const float*)d_in[4];
  const float* attn_W = (const float*)d_in[5];
  // d_in[6] (attn_b) cancels in the softmax -> unused.

  float* out0 = (float*)d_out;                          // (512,128,128)
  float* out1 = out0 + (size_t)NB * NT * ND;            // (512,128,512)

  float* attn_ws = (float*)d_ws;                                     // 256 KB
  unsigned short* hbuf = (unsigned short*)((char*)d_ws + 262144);    // 1 MB
  unsigned int* flags = (unsigned int*)((char*)d_ws + 262144 + 1048576); // 16 KB

  hipMemsetAsync(flags, 0, 16384, stream);
  attn_kernel<<<NB, 128, 0, stream>>>(in, attn_W, out0, attn_ws);
  rec_kernel<<<256, 512, 0, stream>>>(in, W_ih, W_hh, b_ih, b_hh, attn_ws,
                                      hbuf, flags, out1);
}

// Round 16
// 457.528 us; speedup vs baseline: 2.2042x; 1.0151x over previous
//
#include <hip/hip_runtime.h>

// B=512, T-1=128, D=128, H=512. softmax(proj_x + shift[:,None]) == softmax(proj_x)
// => attention is timestep-invariant; only the LSTM recurrence is sequential.
//
// R16 = R14 (471us, proven) + the two SAFE R15 deltas only:
//  (1) HH staging split vmcnt(4)/vmcnt(0): first half of LDS writes overlaps
//      the gather tail (was in R3, lost in the R12 rewrite).
//  (2) eager publish: store each pointwise cell as computed; drain + arrival
//      atomic right after the 2nd store.
// R15's 2-deep pipelined poll (inline-asm s_waitcnt with tied "+v" operand)
// CRASHED — reverted to R14's proven single-probe poll.

typedef __attribute__((ext_vector_type(8))) short short8;
typedef __attribute__((ext_vector_type(4))) float floatx4;
typedef __attribute__((ext_vector_type(2))) float floatx2;
typedef __attribute__((ext_vector_type(4))) unsigned int uintx4;

#define NB 512
#define NT 128
#define ND 128
#define NH 512

// LDS layout (131072 B; > 81920 => 1 block/CU)
#define HH_OFF 0          // h tile [64][512] bf16, swizzled (64 KB)
#define WT0_OFF 65536     // wi tile ping [64][128] bf16, swizzled (16 KB)
#define WT1_OFF 81920     // wi tile pong (16 KB)
#define GT_OFF 98304      // gates [2 kh][64 rows][16 cols][4 gates] f32 (32 KB)
#define GT_PL  16384
#define LDS_BYTES 131072

static __device__ __forceinline__ unsigned short f2bf(float f) {
  unsigned int u = __float_as_uint(f);
  u += 0x7fffu + ((u >> 16) & 1u);   // RNE
  return (unsigned short)(u >> 16);
}
static __device__ __forceinline__ unsigned int cvtpk(float lo, float hi) {
  unsigned int r;
  asm("v_cvt_pk_bf16_f32 %0, %1, %2" : "=v"(r) : "v"(lo), "v"(hi));
  return r;
}
static __device__ __forceinline__ float rcpf(float x) {
  float r;
  asm("v_rcp_f32 %0, %1" : "=v"(r) : "v"(x));
  return r;
}
static __device__ __forceinline__ float sigf(float x) {
  return rcpf(1.f + __expf(-x));
}
static __device__ __forceinline__ float tanh_fast(float x) {
  const float e = __expf(-2.f * fabsf(x));
  const float r = (1.f - e) * rcpf(1.f + e);
  return copysignf(r, x);
}

// ---------------------------------------------------------------------------
// Kernel A: attn[b,d] = softmax_d( sum_t in[b,t,d]*wx[t] ); out0 = attn*in
// ---------------------------------------------------------------------------
__global__ __launch_bounds__(128) void attn_kernel(
    const float* __restrict__ in, const float* __restrict__ attn_W,
    float* __restrict__ out0, float* __restrict__ attn_ws) {
  const int b = blockIdx.x;
  const int d = threadIdx.x;
  __shared__ float wx[NT];
  __shared__ float red[4];
  wx[d] = attn_W[2 * NH + d];
  __syncthreads();
  const float* ib = in + (size_t)b * (NT * ND);
  float p = 0.f;
#pragma unroll 8
  for (int t = 0; t < NT; ++t) p = fmaf(ib[t * ND + d], wx[t], p);
  float m = p;
#pragma unroll
  for (int off = 32; off >= 1; off >>= 1) m = fmaxf(m, __shfl_xor(m, off));
  const int wv = d >> 6;
  if ((d & 63) == 0) red[wv] = m;
  __syncthreads();
  const float M = fmaxf(red[0], red[1]);
  const float e = expf(p - M);
  float s = e;
#pragma unroll
  for (int off = 32; off >= 1; off >>= 1) s += __shfl_xor(s, off);
  if ((d & 63) == 0) red[2 + wv] = s;
  __syncthreads();
  const float a = e / (red[2] + red[3]);
  attn_ws[b * ND + d] = a;
#pragma unroll 4
  for (int t = 0; t < NT; ++t)
    out0[(size_t)b * (NT * ND) + t * ND + d] = a * ib[t * ND + d];
}

// ---------------------------------------------------------------------------
// Kernel C: persistent fused LSTM recurrence. 256 blocks x 512 thr, 1/CU.
// Block (gid=bid&7, sid=bid>>3): batch rows [gid*64,+64), h-cols [sid*16,+16).
// Wave wid: rw=wid&1 (row half), cg=(wid>>1)&1 (gate pair), kh=wid>>2 (K half).
// W fragments in registers (bh[8][2], bwi[2][2]); h + wi + gates in LDS.
// ---------------------------------------------------------------------------
__global__ __launch_bounds__(512, 2) void rec_kernel(
    const float* __restrict__ in, const float* __restrict__ W_ih,
    const float* __restrict__ W_hh, const float* __restrict__ b_ih,
    const float* __restrict__ b_hh, const float* __restrict__ attn_ws,
    unsigned short* __restrict__ hbuf, unsigned int* __restrict__ flags,
    float* __restrict__ out1) {
  __shared__ __align__(16) unsigned char LDS[LDS_BYTES];
  const int tid = threadIdx.x;
  const int bid = blockIdx.x;
  const int gid = bid & 7;
  const int sid = bid >> 3;
  const int bb0 = gid * 64;
  const int n0 = sid * 16;
  const int lane = tid & 63;
  const int wid = tid >> 6;
  const int rw = wid & 1;
  const int cg = (wid >> 1) & 1;
  const int kh = wid >> 2;
  const int colB = lane & 15;
  const int kg = lane >> 4;

  // --- W fragments -> registers (one-time), R14 verbatim ---
  short8 bh[8][2];
  short8 bwi[2][2];
#pragma unroll
  for (int j = 0; j < 2; ++j) {
    const int gate = cg * 2 + j;
    const float* wr_h = W_hh + (size_t)(gate * NH + n0 + colB) * NH;
    const float* wr_i = W_ih + (size_t)(gate * NH + n0 + colB) * ND;
#pragma unroll
    for (int ksl = 0; ksl < 8; ++ksl) {
      const int k0 = (kh * 8 + ksl) * 32 + kg * 8;
      floatx4 f0 = *(const floatx4*)(wr_h + k0);
      floatx4 f1 = *(const floatx4*)(wr_h + k0 + 4);
      short8 s;
#pragma unroll
      for (int i = 0; i < 4; ++i) {
        s[i] = (short)f2bf(f0[i]);
        s[4 + i] = (short)f2bf(f1[i]);
      }
      bh[ksl][j] = s;
    }
#pragma unroll
    for (int ksl = 0; ksl < 2; ++ksl) {
      const int k0 = (kh * 2 + ksl) * 32 + kg * 8;
      floatx4 f0 = *(const floatx4*)(wr_i + k0);
      floatx4 f1 = *(const floatx4*)(wr_i + k0 + 4);
      short8 s;
#pragma unroll
      for (int i = 0; i < 4; ++i) {
        s[i] = (short)f2bf(f0[i]);
        s[4 + i] = (short)f2bf(f1[i]);
      }
      bwi[ksl][j] = s;
    }
  }

  // --- attention weights (t-invariant) ---
  const int rA = tid >> 3;
  const int pA = tid & 7;
  float areg[16];
  {
    const float* ap = attn_ws + (bb0 + rA) * ND + pA * 16;
#pragma unroll
    for (int i = 0; i < 16; ++i) areg[i] = ap[i];
  }
  // --- per-wave gate biases (folded into kh=0 accumulator init) ---
  float bw0 = 0.f, bw1 = 0.f;
  if (kh == 0) {
    const int j0 = (cg * 2 + 0) * NH + n0 + colB;
    const int j1 = (cg * 2 + 1) * NH + n0 + colB;
    bw0 = b_ih[j0] + b_hh[j0];
    bw1 = b_ih[j1] + b_hh[j1];
  }
  const int colC = tid & 15;
  const int jC = n0 + colC;
  float creg0 = 0.f, creg1 = 0.f;

  const int rowa0 = rw * 32 + colB;
  const int rowa1 = rowa0 + 16;
  const int swa = (rowa0 & 7) << 4;
  const int prow = tid >> 4;
  unsigned int* cme = flags + (gid * 32 + sid) * 16;            // my counter
  const unsigned int* fpoll = flags + (gid * 32 + (lane & 31)) * 16;

  // --- prologue: WT0 <- wi_0; prefetch x_1 ---
  floatx4 xr4[4];
  {
    const float* xs = in + ((size_t)(bb0 + rA) * NT + 0) * ND + pA * 16;
#pragma unroll
    for (int i = 0; i < 4; ++i) xr4[i] = *(const floatx4*)(xs + 4 * i);
    unsigned int w[8];
#pragma unroll
    for (int i = 0; i < 8; ++i)
      w[i] = cvtpk(xr4[i >> 1][(i & 1) * 2 + 0] * areg[2 * i],
                   xr4[i >> 1][(i & 1) * 2 + 1] * areg[2 * i + 1]);
    const int base = WT0_OFF + rA * 256;
    const int swp = (rA & 7) << 4;
    uintx4 lo = {w[0], w[1], w[2], w[3]};
    uintx4 hi = {w[4], w[5], w[6], w[7]};
    *(uintx4*)&LDS[base + ((pA * 32) ^ swp)] = lo;
    *(uintx4*)&LDS[base + ((pA * 32 + 16) ^ swp)] = hi;
  }
  {
    const float* xs = in + ((size_t)(bb0 + rA) * NT + 1) * ND + pA * 16;
#pragma unroll
    for (int i = 0; i < 4; ++i) xr4[i] = *(const floatx4*)(xs + 4 * i);
  }
  __syncthreads();

  for (int t = 0; t < NT; ++t) {
    const int wtR = (t & 1) ? WT1_OFF : WT0_OFF;
    const int wtW = (t & 1) ? WT0_OFF : WT1_OFF;

    floatx4 acc00 = {bw0, bw0, bw0, bw0};
    floatx4 acc01 = {bw1, bw1, bw1, bw1};
    floatx4 acc10 = {bw0, bw0, bw0, bw0};
    floatx4 acc11 = {bw1, bw1, bw1, bw1};

    // ---- P1 (pre-poll): wi MFMAs from WT[t&1] + pack wi_{t+1} ----
#pragma unroll
    for (int ksl = 0; ksl < 2; ++ksl) {
      const int k2 = (kh * 2 + ksl) * 64 + kg * 16;
      short8 a0 = *(const short8*)&LDS[wtR + rowa0 * 256 + (k2 ^ swa)];
      short8 a1 = *(const short8*)&LDS[wtR + rowa1 * 256 + (k2 ^ swa)];
      acc00 = __builtin_amdgcn_mfma_f32_16x16x32_bf16(a0, bwi[ksl][0], acc00, 0, 0, 0);
      acc01 = __builtin_amdgcn_mfma_f32_16x16x32_bf16(a0, bwi[ksl][1], acc01, 0, 0, 0);
      acc10 = __builtin_amdgcn_mfma_f32_16x16x32_bf16(a1, bwi[ksl][0], acc10, 0, 0, 0);
      acc11 = __builtin_amdgcn_mfma_f32_16x16x32_bf16(a1, bwi[ksl][1], acc11, 0, 0, 0);
    }
    unsigned int w[8];
#pragma unroll
    for (int i = 0; i < 8; ++i)
      w[i] = cvtpk(xr4[i >> 1][(i & 1) * 2 + 0] * areg[2 * i],
                   xr4[i >> 1][(i & 1) * 2 + 1] * areg[2 * i + 1]);

    if (t > 0) {
      // ---- P2: ALL waves poll the 32 block-counters for >= 8t (R14) ----
      {
        const unsigned int target = (unsigned int)(t << 3);   // 8*t
        unsigned int v;
        do {
          asm volatile("global_load_dword %0, %1, off sc0 sc1\n\ts_waitcnt vmcnt(0)"
                       : "=v"(v) : "v"(fpoll) : "memory");
        } while (!__all(v >= target));
      }
      // ---- P3: issue full h-tile gather (1KB coalesced per load) ----
      const unsigned short* hsrc = hbuf + ((t & 1) ? (size_t)(NB * NH) : 0);
      uintx4 hq[8];
#pragma unroll
      for (int p = 0; p < 8; ++p) {
        const int idx = p * 512 + tid;
        const int r = idx >> 6, s = idx & 63;
        const unsigned short* src = hsrc + (size_t)(bb0 + r) * NH + s * 8;
        asm volatile("global_load_dwordx4 %0, %1, off sc0 sc1"
                     : "=v"(hq[p]) : "v"(src) : "memory");
      }
      // ---- shadow: WT[(t+1)&1] <- wi_{t+1} (LDS, doesn't touch vmcnt) ----
      {
        const int base = wtW + rA * 256;
        const int swp = (rA & 7) << 4;
        uintx4 lo = {w[0], w[1], w[2], w[3]};
        uintx4 hi = {w[4], w[5], w[6], w[7]};
        *(uintx4*)&LDS[base + ((pA * 32) ^ swp)] = lo;
        *(uintx4*)&LDS[base + ((pA * 32 + 16) ^ swp)] = hi;
      }
      // ---- P4: HH stage, split to overlap the gather tail ----
      asm volatile("s_waitcnt vmcnt(4)" ::: "memory");   // hq0..3 done
      __builtin_amdgcn_sched_barrier(0);
#pragma unroll
      for (int p = 0; p < 4; ++p) {
        const int idx = p * 512 + tid;
        const int r = idx >> 6, s = idx & 63;
        *(uintx4*)&LDS[HH_OFF + r * 1024 + ((s * 16) ^ ((r & 7) << 4))] = hq[p];
      }
      asm volatile("s_waitcnt vmcnt(0)" ::: "memory");
      __builtin_amdgcn_sched_barrier(0);
#pragma unroll
      for (int p = 4; p < 8; ++p) {
        const int idx = p * 512 + tid;
        const int r = idx >> 6, s = idx & 63;
        *(uintx4*)&LDS[HH_OFF + r * 1024 + ((s * 16) ^ ((r & 7) << 4))] = hq[p];
      }
      __syncthreads();                                   // (b)
      // ---- P5: h MFMAs ----
#pragma unroll
      for (int ksl = 0; ksl < 8; ++ksl) {
        const int k2 = (kh * 8 + ksl) * 64 + kg * 16;
        short8 a0 = *(const short8*)&LDS[HH_OFF + rowa0 * 1024 + (k2 ^ swa)];
        short8 a1 = *(const short8*)&LDS[HH_OFF + rowa1 * 1024 + (k2 ^ swa)];
        acc00 = __builtin_amdgcn_mfma_f32_16x16x32_bf16(a0, bh[ksl][0], acc00, 0, 0, 0);
        acc01 = __builtin_amdgcn_mfma_f32_16x16x32_bf16(a0, bh[ksl][1], acc01, 0, 0, 0);
        acc10 = __builtin_amdgcn_mfma_f32_16x16x32_bf16(a1, bh[ksl][0], acc10, 0, 0, 0);
        acc11 = __builtin_amdgcn_mfma_f32_16x16x32_bf16(a1, bh[ksl][1], acc11, 0, 0, 0);
      }
    } else {
      // t == 0: WT1 <- wi_1 (different buffer => safe without barrier)
      const int base = wtW + rA * 256;
      const int swp = (rA & 7) << 4;
      uintx4 lo = {w[0], w[1], w[2], w[3]};
      uintx4 hi = {w[4], w[5], w[6], w[7]};
      *(uintx4*)&LDS[base + ((pA * 32) ^ swp)] = lo;
      *(uintx4*)&LDS[base + ((pA * 32 + 16) ^ swp)] = hi;
    }
    // ---- P6: gate pairs -> GT[kh][row][col][4] (cell-major, b64 writes) ----
#pragma unroll
    for (int i = 0; i < 2; ++i)
#pragma unroll
      for (int r = 0; r < 4; ++r) {
        const int row = rw * 32 + i * 16 + kg * 4 + r;
        const int sw = ((kg * 4 + r) & 7) << 4;
        floatx2 v;
        v[0] = i ? acc10[r] : acc00[r];
        v[1] = i ? acc11[r] : acc01[r];
        *(floatx2*)&LDS[GT_OFF + kh * GT_PL + row * 256 +
                        ((colB * 16 + cg * 8) ^ sw)] = v;
      }
    __syncthreads();                                     // (c)
    // ---- P7: pointwise + EAGER publish (store cell as computed) ----
    float hn0, hn1;
    unsigned short* hdst = hbuf + (((t + 1) & 1) ? (size_t)(NB * NH) : 0) +
                           (size_t)(bb0 + prow) * NH + jC;
    const int pw0 = prow * 256 + ((colC * 16) ^ ((prow & 7) << 4));
    const int pw1 = pw0 + 32 * 256;                      // (prow+32)&7 == prow&7
    float o0, o1;
    {
      floatx4 gA = *(const floatx4*)&LDS[GT_OFF + pw0];
      floatx4 gB = *(const floatx4*)&LDS[GT_OFF + GT_PL + pw0];
      const float gi = gA[0] + gB[0];
      const float gf = gA[1] + gB[1];
      const float gg = gA[2] + gB[2];
      const float go = gA[3] + gB[3];
      const float cn = sigf(gf) * creg0 + sigf(gi) * tanh_fast(gg);
      hn0 = sigf(go) * tanh_fast(cn);
      creg0 = cn;
      o0 = __shfl_xor(hn0, 1);
      if (!(tid & 1)) {
        const unsigned int d0 = cvtpk(hn0, o0);
        asm volatile("global_store_dword %0, %1, off sc0 sc1" :: "v"(hdst), "v"(d0) : "memory");
      }
    }
    {
      floatx4 gC = *(const floatx4*)&LDS[GT_OFF + pw1];
      floatx4 gD = *(const floatx4*)&LDS[GT_OFF + GT_PL + pw1];
      const float gi1 = gC[0] + gD[0];
      const float gf1 = gC[1] + gD[1];
      const float gg1 = gC[2] + gD[2];
      const float go1 = gC[3] + gD[3];
      const float cn1 = sigf(gf1) * creg1 + sigf(gi1) * tanh_fast(gg1);
      hn1 = sigf(go1) * tanh_fast(cn1);
      creg1 = cn1;
      o1 = __shfl_xor(hn1, 1);
      if (!(tid & 1)) {
        unsigned short* hdst2 = hdst + (size_t)32 * NH;
        const unsigned int d1 = cvtpk(hn1, o1);
        asm volatile("global_store_dword %0, %1, off sc0 sc1" :: "v"(hdst2), "v"(d1) : "memory");
      }
    }
    // ---- per-wave publish: own stores ACK'd -> +1 on block counter ----
    asm volatile("s_waitcnt vmcnt(0)" ::: "memory");
    if (lane == 0) atomicAdd(cme, 1u);
    // ---- off-critical-path: out1 (8B lane-pair packed) + x prefetch ----
    if (!(tid & 1)) {
      floatx2 v0 = {hn0, o0};
      floatx2 v1 = {hn1, o1};
      __builtin_nontemporal_store(v0,
          (floatx2*)&out1[((size_t)(bb0 + prow) * NT + t) * NH + jC]);
      __builtin_nontemporal_store(v1,
          (floatx2*)&out1[((size_t)(bb0 + 32 + prow) * NT + t) * NH + jC]);
    }
    {
      const int tx = (t + 2 < NT) ? (t + 2) : (NT - 1);
      const float* xs = in + ((size_t)(bb0 + rA) * NT + tx) * ND + pA * 16;
#pragma unroll
      for (int i = 0; i < 4; ++i) xr4[i] = *(const floatx4*)(xs + 4 * i);
    }
  }
}

// ---------------------------------------------------------------------------
extern "C" void kernel_launch(void* const* d_in, const int* in_sizes, int n_in,
                              void* d_out, int out_size, void* d_ws, size_t ws_size,
                              hipStream_t stream) {
  (void)in_sizes; (void)n_in; (void)out_size; (void)ws_size;
  const float* in     = (const float*)d_in[0];
  const float* W_ih   = (const float*)d_in[1];
  const float* W_hh   = (const float*)d_in[2];
  const float* b_ih   = (const float*)d_in[3];
  const float* b_hh   = (const float*)d_in[4];
  const float* attn_W = (const float*)d_in[5];
  // d_in[6] (attn_b) cancels in the softmax -> unused.

  float* out0 = (float*)d_out;                          // (512,128,128)
  float* out1 = out0 + (size_t)NB * NT * ND;            // (512,128,512)

  float* attn_ws = (float*)d_ws;                                     // 256 KB
  unsigned short* hbuf = (unsigned short*)((char*)d_ws + 262144);    // 1 MB
  unsigned int* flags = (unsigned int*)((char*)d_ws + 262144 + 1048576); // 16 KB

  hipMemsetAsync(flags, 0, 16384, stream);
  attn_kernel<<<NB, 128, 0, stream>>>(in, attn_W, out0, attn_ws);
  rec_kernel<<<256, 512, 0, stream>>>(in, W_ih, W_hh, b_ih, b_hh, attn_ws,
                                      hbuf, flags, out1);
}